// Round 8
// baseline (70.315 us; speedup 1.0000x reference)
//
#include <hip/hip_runtime.h>
#include <hip/hip_bf16.h>

#define B_ 8
#define C_ 256
#define L_ 1024
#define NH_ 8
#define EPS_ 1e-5f

typedef __attribute__((ext_vector_type(8))) short bf16x8;
typedef __attribute__((ext_vector_type(4))) float f32x4;

static __device__ inline ushort f2bf(float f) {
  union { __hip_bfloat16 b; ushort u; } c;
  c.b = __float2bfloat16(f);
  return c.u;
}

// ---------------------------------------------------------------------------
// Kernel A: blocks 0-255: weight fp32->bf16 convert; blocks 256-511:
// GroupNorm + depthwise conv k=3, output TRANSPOSED bf16 ht[B][L][256]
// ---------------------------------------------------------------------------
__global__ __launch_bounds__(256) void gnw_kernel(
    const float* __restrict__ x, const float* __restrict__ gamma,
    const float* __restrict__ beta, const float* __restrict__ dw,
    const float4* __restrict__ qw, const float4* __restrict__ ow,
    uint2* __restrict__ wq, uint2* __restrict__ wo_,
    ushort* __restrict__ ht) {
  __shared__ float hn[8 * L_];
  __shared__ float ws0[4], ws1[4];
  int t = threadIdx.x;
  if (blockIdx.x < 256) {
    int id = blockIdx.x * 256 + t;
    float4 v;
    uint2* dst;
    if (id < 49152) { v = qw[id]; dst = wq + id; }
    else { v = ow[id - 49152]; dst = wo_ + (id - 49152); }
    union { ushort s[4]; uint2 u; } p;
    p.s[0] = f2bf(v.x); p.s[1] = f2bf(v.y); p.s[2] = f2bf(v.z); p.s[3] = f2bf(v.w);
    *dst = p.u;
    return;
  }
  int blk = blockIdx.x - 256;     // b*32 + g
  int b = blk >> 5, g = blk & 31;
  const size_t base = ((size_t)(b * C_ + g * 8)) * L_;

  float s = 0.f, ss = 0.f;
  float vals[32];
#pragma unroll
  for (int i = 0; i < 32; ++i) {
    int e = t + 256 * i;
    float v = x[base + e];
    vals[i] = v;
    s += v; ss += v * v;
  }
#pragma unroll
  for (int off = 32; off >= 1; off >>= 1) {
    s  += __shfl_xor(s, off);
    ss += __shfl_xor(ss, off);
  }
  int wave = t >> 6;
  if ((t & 63) == 0) { ws0[wave] = s; ws1[wave] = ss; }
  __syncthreads();
  s  = ws0[0] + ws0[1] + ws0[2] + ws0[3];
  ss = ws1[0] + ws1[1] + ws1[2] + ws1[3];
  float mean = s * (1.f / 8192.f);
  float var = ss * (1.f / 8192.f) - mean * mean;
  float rstd = rsqrtf(var + EPS_);

#pragma unroll
  for (int i = 0; i < 32; ++i) {
    int e = t + 256 * i;
    int c = g * 8 + (e >> 10);
    float sc = gamma[c] * rstd;
    hn[e] = (vals[i] - mean) * sc + beta[c];
  }
  __syncthreads();
  float r[32];
#pragma unroll
  for (int i = 0; i < 32; ++i) {
    int e = t + 256 * i;
    int l = e & 1023;
    int c = g * 8 + (i >> 2);
    float w0 = dw[c * 3 + 0], w1 = dw[c * 3 + 1], w2 = dw[c * 3 + 2];
    float a = (l > 0) ? hn[e - 1] : 0.f;
    float m = hn[e];
    float z = (l < 1023) ? hn[e + 1] : 0.f;
    r[i] = w0 * a + w1 * m + w2 * z;
  }
#pragma unroll
  for (int li = 0; li < 4; ++li) {
    int l = t + 256 * li;
    union { ushort s8[8]; uint4 u; } pk;
#pragma unroll
    for (int cl = 0; cl < 8; ++cl) pk.s8[cl] = f2bf(r[4 * cl + li]);
    *(uint4*)(ht + ((size_t)(b * L_ + l)) * 256 + g * 8) = pk.u;
  }
}

// ---------------------------------------------------------------------------
// Kernel B: qkv pointwise conv via MFMA, fused repack epilogue.
// Q is PRE-SCALED by 1/sqrt(C)*log2(e) so attention needs no per-elem scale.
// ---------------------------------------------------------------------------
__global__ __launch_bounds__(256) void qkv_fused_kernel(
    const ushort* __restrict__ Xt, const ushort* __restrict__ Wb,
    const float* __restrict__ bias, ushort* __restrict__ qt,
    ushort* __restrict__ kt, ushort* __restrict__ vb) {
  int bx = blockIdx.x, head = blockIdx.y, b = blockIdx.z;
  int bh = b * 8 + head;
  int t = threadIdx.x;
  int w = t >> 6, l = t & 63;
  int g = l >> 4, ln = l & 15;
  int wl = w >> 1, wo = w & 1;
  int lbase = bx * 128 + wl * 64;

  const ushort* xp = Xt + ((size_t)b * L_ + lbase) * 256;
  const ushort* wp = Wb + (size_t)(head * 96 + wo * 48) * 256;

  f32x4 acc[4][3];
#pragma unroll
  for (int ml = 0; ml < 4; ++ml)
#pragma unroll
    for (int nn = 0; nn < 3; ++nn) acc[ml][nn] = (f32x4){0.f, 0.f, 0.f, 0.f};

  for (int c0 = 0; c0 < 256; c0 += 32) {
    bf16x8 af[4], bf[3];
#pragma unroll
    for (int ml = 0; ml < 4; ++ml)
      af[ml] = *(const bf16x8*)(xp + (size_t)(16 * ml + ln) * 256 + c0 + 8 * g);
#pragma unroll
    for (int nn = 0; nn < 3; ++nn)
      bf[nn] = *(const bf16x8*)(wp + (size_t)(16 * nn + ln) * 256 + c0 + 8 * g);
#pragma unroll
    for (int ml = 0; ml < 4; ++ml)
#pragma unroll
      for (int nn = 0; nn < 3; ++nn)
        acc[ml][nn] = __builtin_amdgcn_mfma_f32_16x16x32_bf16(af[ml], bf[nn], acc[ml][nn], 0, 0, 0);
  }

  // bias
#pragma unroll
  for (int nn = 0; nn < 3; ++nn) {
    float bs = bias[head * 96 + wo * 48 + 16 * nn + ln];
#pragma unroll
    for (int ml = 0; ml < 4; ++ml)
#pragma unroll
      for (int r = 0; r < 4; ++r) acc[ml][nn][r] += bs;
  }

  __shared__ ushort tr[5120];
  const float QSC = 0.0625f * 1.44269504f;   // 1/sqrt(256) * log2(e)

  // rounds 0 (q, scaled), 1 (k): transpose to [l][d] (pad 40), write [bh][l][32]
  for (int rk = 0; rk < 2; ++rk) {
    float sc = rk ? 1.f : QSC;
    __syncthreads();
#pragma unroll
    for (int nn = 0; nn < 3; ++nn) {
      int ocl0 = wo * 48 + 16 * nn;
      if (ocl0 >= rk * 32 && ocl0 < rk * 32 + 32) {
        int d = ocl0 - rk * 32 + ln;
#pragma unroll
        for (int ml = 0; ml < 4; ++ml) {
          int lrow = wl * 64 + 16 * ml + 4 * g;
#pragma unroll
          for (int r = 0; r < 4; ++r)
            tr[(lrow + r) * 40 + d] = f2bf(acc[ml][nn][r] * sc);
        }
      }
    }
    __syncthreads();
    {
      int row = t >> 1, half = t & 1;
      uint4 v0 = *(const uint4*)&tr[row * 40 + half * 16];
      uint4 v1 = *(const uint4*)&tr[row * 40 + half * 16 + 8];
      ushort* dst = (rk ? kt : qt) +
                    ((size_t)bh * L_ + bx * 128 + row) * 32 + half * 16;
      *(uint4*)dst = v0;
      *(uint4*)(dst + 8) = v1;
    }
  }

  // round 2 (v): [d][l] (pad 136), PI-permute on global write
  __syncthreads();
  if (wo == 1) {
#pragma unroll
    for (int nn = 1; nn < 3; ++nn) {
      int d = 16 * (nn - 1) + ln;
#pragma unroll
      for (int ml = 0; ml < 4; ++ml) {
        int lc = wl * 64 + 16 * ml + 4 * g;
        union { ushort s[4]; uint2 u; } pk;
#pragma unroll
        for (int r = 0; r < 4; ++r) pk.s[r] = f2bf(acc[ml][nn][r]);
        *(uint2*)&tr[d * 136 + lc] = pk.u;
      }
    }
  }
  __syncthreads();
  {
    int d = t >> 3, s0 = t & 7;
    ushort* vdst = vb + ((size_t)bh * 32 + d) * L_ + bx * 128;
#pragma unroll
    for (int c = 0; c < 2; ++c) {
      int ch = s0 + 8 * c;
      int jj = ch >> 2, gg = ch & 3;
      uint2 lo = *(const uint2*)&tr[d * 136 + 32 * jj + 4 * gg];
      uint2 hi = *(const uint2*)&tr[d * 136 + 32 * jj + 16 + 4 * gg];
      *(uint4*)(vdst + 32 * jj + 8 * gg) = make_uint4(lo.x, lo.y, hi.x, hi.y);
    }
  }
}

// ---------------------------------------------------------------------------
// Kernel D: out pointwise conv via MFMA + residual (fp32 out).
// OCT=16: block = 128l x 32oc, grid (8, 8, 8) = 512 blocks (2/CU).
// ---------------------------------------------------------------------------
template <int OCT>
__global__ __launch_bounds__(256) void pconv_mfma_kernel(
    const ushort* __restrict__ Xt, const ushort* __restrict__ Wb,
    const float* __restrict__ bias, const float* __restrict__ resid,
    float* __restrict__ out, int OC) {
  constexpr int NN = OCT / 16;
  int b = blockIdx.z;
  int t = threadIdx.x;
  int w = t >> 6, l = t & 63;
  int g = l >> 4, ln = l & 15;
  int wl = w >> 1, wo = w & 1;
  int lbase = blockIdx.x * 128 + wl * 64;
  int ocbase = blockIdx.y * (2 * OCT) + wo * OCT;

  const ushort* xp = Xt + ((size_t)b * L_ + lbase) * 256;
  const ushort* wp = Wb + (size_t)ocbase * 256;

  f32x4 acc[4][NN];
#pragma unroll
  for (int ml = 0; ml < 4; ++ml)
#pragma unroll
    for (int nn = 0; nn < NN; ++nn) acc[ml][nn] = (f32x4){0.f, 0.f, 0.f, 0.f};

  for (int c0 = 0; c0 < 256; c0 += 32) {
    bf16x8 af[4], bf[NN];
#pragma unroll
    for (int ml = 0; ml < 4; ++ml)
      af[ml] = *(const bf16x8*)(xp + (size_t)(16 * ml + ln) * 256 + c0 + 8 * g);
#pragma unroll
    for (int nn = 0; nn < NN; ++nn)
      bf[nn] = *(const bf16x8*)(wp + (size_t)(16 * nn + ln) * 256 + c0 + 8 * g);
#pragma unroll
    for (int ml = 0; ml < 4; ++ml)
#pragma unroll
      for (int nn = 0; nn < NN; ++nn)
        acc[ml][nn] = __builtin_amdgcn_mfma_f32_16x16x32_bf16(af[ml], bf[nn], acc[ml][nn], 0, 0, 0);
  }

#pragma unroll
  for (int nn = 0; nn < NN; ++nn) {
    int oc = ocbase + 16 * nn + ln;
    float bs = bias[oc];
#pragma unroll
    for (int ml = 0; ml < 4; ++ml) {
      int lr = lbase + 16 * ml + 4 * g;
      size_t ob = ((size_t)b * OC + oc) * L_ + lr;
      float4 rd = *(const float4*)(resid + ob);
      float4 st = make_float4(acc[ml][nn][0] + bs + rd.x, acc[ml][nn][1] + bs + rd.y,
                              acc[ml][nn][2] + bs + rd.z, acc[ml][nn][3] + bs + rd.w);
      *(float4*)(out + ob) = st;
    }
  }
}

// ---------------------------------------------------------------------------
// Kernel C: MFMA flash attention, no max-subtraction. Wave = 16q, block =
// 4 waves = 64q, grid 1024 (16 qtiles x 64 bh). dbuf LDS staging (padded,
// conflict-free); epilogue tile overlays dead K buffer 0. 4 blocks/CU.
// ---------------------------------------------------------------------------
__global__ __launch_bounds__(256) void attn_mfma_kernel(
    const ushort* __restrict__ qt, const ushort* __restrict__ kt,
    const ushort* __restrict__ vb, ushort* __restrict__ ot) {
  const int id = blockIdx.x;
  const int bh = ((id & 7) << 3) | (id >> 7);
  const int qtile = (id >> 3) & 15;
  const int b = bh >> 3, hh = bh & 7;
  const int t = threadIdx.x;
  const int w = t >> 6, l = t & 63;
  const int g = l >> 4, ln = l & 15;
  const int q0b = qtile * 64;
  const int q0 = q0b + w * 16;

  // smem map (ushorts): K0 @0 (5120), K1 @5120, V0 @10240 (4352), V1 @14592
  // epilogue otile (64*40=2560) overlays K0 (dead after tt==6 barrier).
  __shared__ __align__(16) ushort smem[18944];    // 37,888 B

  const ushort* qbase = qt + (size_t)bh * (L_ * 32);
  const ushort* kbase = kt + (size_t)bh * (L_ * 32);
  const ushort* vbase = vb + (size_t)bh * (32 * L_);

  // staging geometry
  const int krow = t >> 1, khalf = t & 1;
  const ushort* kg = kbase + krow * 32 + khalf * 16;
  const int kwo = krow * 40 + khalf * 16;
  const int vrow = t >> 3, vc = (t & 7) * 16;
  const ushort* vg = vbase + (size_t)vrow * L_ + vc;
  const int vwo = vrow * 136 + vc;

  const f32x4 z4 = {0.f, 0.f, 0.f, 0.f};
  const bf16x8 bq = *(const bf16x8*)(qbase + (size_t)(q0 + ln) * 32 + g * 8);

  union { ushort s[8]; bf16x8 v; } onesu;
#pragma unroll
  for (int i = 0; i < 8; ++i) onesu.s[i] = 0x3F80;  // bf16 1.0
  const bf16x8 ones = onesu.v;

  f32x4 oacc[2] = {z4, z4};
  f32x4 oaccS = z4;

  // prologue: stage tile 0
  uint4 ka0, ka1, va0, va1;
  ka0 = *(const uint4*)kg;       ka1 = *(const uint4*)(kg + 8);
  va0 = *(const uint4*)vg;       va1 = *(const uint4*)(vg + 8);
  __builtin_amdgcn_sched_barrier(0);
  *(uint4*)&smem[kwo] = ka0;             *(uint4*)&smem[kwo + 8] = ka1;
  *(uint4*)&smem[10240 + vwo] = va0;     *(uint4*)&smem[10240 + vwo + 8] = va1;
  asm volatile("s_waitcnt lgkmcnt(0)" ::: "memory");
  __builtin_amdgcn_s_barrier();
  __builtin_amdgcn_sched_barrier(0);

  for (int tt = 0; tt < 8; ++tt) {
    const int cur = tt & 1;
    if (tt < 7) {
      ka0 = *(const uint4*)(kg + (tt + 1) * 4096);
      ka1 = *(const uint4*)(kg + (tt + 1) * 4096 + 8);
      va0 = *(const uint4*)(vg + (tt + 1) * 128);
      va1 = *(const uint4*)(vg + (tt + 1) * 128 + 8);
    }
    __builtin_amdgcn_sched_barrier(0);

    const ushort* Kc = &smem[cur * 5120];
    const ushort* Vc = &smem[10240 + cur * 4352];

    // QK^T  (S already in log2-units thanks to Q pre-scale)
    f32x4 sacc[8];
#pragma unroll
    for (int mk = 0; mk < 8; ++mk) {
      bf16x8 ak = *(const bf16x8*)(Kc + (16 * mk + ln) * 40 + g * 8);
      sacc[mk] = __builtin_amdgcn_mfma_f32_16x16x32_bf16(ak, bq, z4, 0, 0, 0);
    }

    // exp + pack to bf16 (no max subtraction, no cross-lane ops)
    uint upk[8][2];
#pragma unroll
    for (int mk = 0; mk < 8; ++mk) {
      float e0 = exp2f(sacc[mk][0]);
      float e1 = exp2f(sacc[mk][1]);
      float e2 = exp2f(sacc[mk][2]);
      float e3 = exp2f(sacc[mk][3]);
      uint u0, u1;
      asm("v_cvt_pk_bf16_f32 %0, %1, %2" : "=v"(u0) : "v"(e0), "v"(e1));
      asm("v_cvt_pk_bf16_f32 %0, %1, %2" : "=v"(u1) : "v"(e2), "v"(e3));
      upk[mk][0] = u0; upk[mk][1] = u1;
    }

    // PV + denominator
#pragma unroll
    for (int ks = 0; ks < 4; ++ks) {
      union { uint u[4]; bf16x8 v; } pb;
      pb.u[0] = upk[2 * ks][0];     pb.u[1] = upk[2 * ks][1];
      pb.u[2] = upk[2 * ks + 1][0]; pb.u[3] = upk[2 * ks + 1][1];
      oaccS = __builtin_amdgcn_mfma_f32_16x16x32_bf16(ones, pb.v, oaccS, 0, 0, 0);
#pragma unroll
      for (int md = 0; md < 2; ++md) {
        bf16x8 av = *(const bf16x8*)(Vc + (16 * md + ln) * 136 + 32 * ks + 8 * g);
        oacc[md] = __builtin_amdgcn_mfma_f32_16x16x32_bf16(av, pb.v, oacc[md], 0, 0, 0);
      }
    }

    __builtin_amdgcn_sched_barrier(0);
    if (tt < 7) {
      const int nxt = cur ^ 1;
      *(uint4*)&smem[nxt * 5120 + kwo] = ka0;
      *(uint4*)&smem[nxt * 5120 + kwo + 8] = ka1;
      *(uint4*)&smem[10240 + nxt * 4352 + vwo] = va0;
      *(uint4*)&smem[10240 + nxt * 4352 + vwo + 8] = va1;
      asm volatile("s_waitcnt lgkmcnt(0)" ::: "memory");
      __builtin_amdgcn_s_barrier();
      __builtin_amdgcn_sched_barrier(0);
    }
  }

  // epilogue: normalize, LDS transpose (overlay on K0), write ot[B][L][256]
  ushort* otile = &smem[0];                  // [64][40]
  float rl = 1.f / oaccS[0];
  int q_loc = w * 16 + ln;
#pragma unroll
  for (int md = 0; md < 2; ++md) {
    ushort4 pk;
    pk.x = f2bf(oacc[md][0] * rl); pk.y = f2bf(oacc[md][1] * rl);
    pk.z = f2bf(oacc[md][2] * rl); pk.w = f2bf(oacc[md][3] * rl);
    *(ushort4*)&otile[q_loc * 40 + 16 * md + 4 * g] = pk;
  }
  __syncthreads();
  {
    int row = t >> 2, qu = t & 3;
    uint4 v = *(const uint4*)&otile[row * 40 + qu * 8];
    *(uint4*)(ot + ((size_t)(b * L_ + q0b + row)) * 256 + hh * 32 + qu * 8) = v;
  }
}

// ---------------------------------------------------------------------------
extern "C" void kernel_launch(void* const* d_in, const int* in_sizes, int n_in,
                              void* d_out, int out_size, void* d_ws, size_t ws_size,
                              hipStream_t stream) {
  const float* x      = (const float*)d_in[0];
  const float* gamma  = (const float*)d_in[1];
  const float* beta   = (const float*)d_in[2];
  const float* dw     = (const float*)d_in[3];
  const float* qkv_w  = (const float*)d_in[4];
  const float* qkv_b  = (const float*)d_in[5];
  const float* out_w  = (const float*)d_in[6];
  const float* out_b  = (const float*)d_in[7];
  float* out = (float*)d_out;

  char* ws = (char*)d_ws;
  ushort* ht   = (ushort*)(ws);                   // 4 MiB @0  (dead after qkv)
  ushort* qtb  = (ushort*)(ws + (16u << 20));     // 4 MiB @16
  ushort* ktb  = (ushort*)(ws + (20u << 20));     // 4 MiB @20
  ushort* vbb  = (ushort*)(ws + (24u << 20));     // 4 MiB @24
  ushort* otb  = (ushort*)(ws);                   // 4 MiB @0  (reuse ht)
  ushort* wq   = (ushort*)(ws + (28u << 20));     // 384 KiB @28M
  ushort* wo   = (ushort*)(ws + (28u << 20) + (512u << 10));  // 128 KiB

  gnw_kernel<<<512, 256, 0, stream>>>(x, gamma, beta, dw,
                                      (const float4*)qkv_w, (const float4*)out_w,
                                      (uint2*)wq, (uint2*)wo, ht);
  qkv_fused_kernel<<<dim3(8, 8, B_), 256, 0, stream>>>(ht, wq, qkv_b, qtb, ktb, vbb);
  attn_mfma_kernel<<<1024, 256, 0, stream>>>(qtb, ktb, vbb, otb);
  pconv_mfma_kernel<16><<<dim3(8, 8, B_), 256, 0, stream>>>(
      otb, wo, out_b, x, out, 256);
}

// Round 11
// 62.880 us; speedup vs baseline: 1.1182x; 1.1182x over previous
//
#include <hip/hip_runtime.h>
#include <hip/hip_bf16.h>

#define B_ 8
#define C_ 256
#define L_ 1024
#define NH_ 8
#define EPS_ 1e-5f

typedef __attribute__((ext_vector_type(8))) short bf16x8;
typedef __attribute__((ext_vector_type(4))) float f32x4;

static __device__ inline ushort f2bf(float f) {
  union { __hip_bfloat16 b; ushort u; } c;
  c.b = __float2bfloat16(f);
  return c.u;
}

// ---------------------------------------------------------------------------
// Kernel A: blocks 0-255: weight fp32->bf16 convert; blocks 256-511:
// GroupNorm + depthwise conv k=3, output TRANSPOSED bf16 ht[B][L][256]
// ---------------------------------------------------------------------------
__global__ __launch_bounds__(256) void gnw_kernel(
    const float* __restrict__ x, const float* __restrict__ gamma,
    const float* __restrict__ beta, const float* __restrict__ dw,
    const float4* __restrict__ qw, const float4* __restrict__ ow,
    uint2* __restrict__ wq, uint2* __restrict__ wo_,
    ushort* __restrict__ ht) {
  __shared__ float hn[8 * L_];
  __shared__ float ws0[4], ws1[4];
  int t = threadIdx.x;
  if (blockIdx.x < 256) {
    int id = blockIdx.x * 256 + t;
    float4 v;
    uint2* dst;
    if (id < 49152) { v = qw[id]; dst = wq + id; }
    else { v = ow[id - 49152]; dst = wo_ + (id - 49152); }
    union { ushort s[4]; uint2 u; } p;
    p.s[0] = f2bf(v.x); p.s[1] = f2bf(v.y); p.s[2] = f2bf(v.z); p.s[3] = f2bf(v.w);
    *dst = p.u;
    return;
  }
  int blk = blockIdx.x - 256;     // b*32 + g
  int b = blk >> 5, g = blk & 31;
  const size_t base = ((size_t)(b * C_ + g * 8)) * L_;

  float s = 0.f, ss = 0.f;
  float vals[32];
#pragma unroll
  for (int i = 0; i < 32; ++i) {
    int e = t + 256 * i;
    float v = x[base + e];
    vals[i] = v;
    s += v; ss += v * v;
  }
#pragma unroll
  for (int off = 32; off >= 1; off >>= 1) {
    s  += __shfl_xor(s, off);
    ss += __shfl_xor(ss, off);
  }
  int wave = t >> 6;
  if ((t & 63) == 0) { ws0[wave] = s; ws1[wave] = ss; }
  __syncthreads();
  s  = ws0[0] + ws0[1] + ws0[2] + ws0[3];
  ss = ws1[0] + ws1[1] + ws1[2] + ws1[3];
  float mean = s * (1.f / 8192.f);
  float var = ss * (1.f / 8192.f) - mean * mean;
  float rstd = rsqrtf(var + EPS_);

#pragma unroll
  for (int i = 0; i < 32; ++i) {
    int e = t + 256 * i;
    int c = g * 8 + (e >> 10);
    float sc = gamma[c] * rstd;
    hn[e] = (vals[i] - mean) * sc + beta[c];
  }
  __syncthreads();
  float r[32];
#pragma unroll
  for (int i = 0; i < 32; ++i) {
    int e = t + 256 * i;
    int l = e & 1023;
    int c = g * 8 + (i >> 2);
    float w0 = dw[c * 3 + 0], w1 = dw[c * 3 + 1], w2 = dw[c * 3 + 2];
    float a = (l > 0) ? hn[e - 1] : 0.f;
    float m = hn[e];
    float z = (l < 1023) ? hn[e + 1] : 0.f;
    r[i] = w0 * a + w1 * m + w2 * z;
  }
#pragma unroll
  for (int li = 0; li < 4; ++li) {
    int l = t + 256 * li;
    union { ushort s8[8]; uint4 u; } pk;
#pragma unroll
    for (int cl = 0; cl < 8; ++cl) pk.s8[cl] = f2bf(r[4 * cl + li]);
    *(uint4*)(ht + ((size_t)(b * L_ + l)) * 256 + g * 8) = pk.u;
  }
}

// ---------------------------------------------------------------------------
// Kernel B: qkv pointwise conv via MFMA, fused repack epilogue.
// Q is PRE-SCALED by 1/sqrt(C)*log2(e) so attention needs no per-elem scale.
// ---------------------------------------------------------------------------
__global__ __launch_bounds__(256) void qkv_fused_kernel(
    const ushort* __restrict__ Xt, const ushort* __restrict__ Wb,
    const float* __restrict__ bias, ushort* __restrict__ qt,
    ushort* __restrict__ kt, ushort* __restrict__ vb) {
  int bx = blockIdx.x, head = blockIdx.y, b = blockIdx.z;
  int bh = b * 8 + head;
  int t = threadIdx.x;
  int w = t >> 6, l = t & 63;
  int g = l >> 4, ln = l & 15;
  int wl = w >> 1, wo = w & 1;
  int lbase = bx * 128 + wl * 64;

  const ushort* xp = Xt + ((size_t)b * L_ + lbase) * 256;
  const ushort* wp = Wb + (size_t)(head * 96 + wo * 48) * 256;

  f32x4 acc[4][3];
#pragma unroll
  for (int ml = 0; ml < 4; ++ml)
#pragma unroll
    for (int nn = 0; nn < 3; ++nn) acc[ml][nn] = (f32x4){0.f, 0.f, 0.f, 0.f};

  for (int c0 = 0; c0 < 256; c0 += 32) {
    bf16x8 af[4], bf[3];
#pragma unroll
    for (int ml = 0; ml < 4; ++ml)
      af[ml] = *(const bf16x8*)(xp + (size_t)(16 * ml + ln) * 256 + c0 + 8 * g);
#pragma unroll
    for (int nn = 0; nn < 3; ++nn)
      bf[nn] = *(const bf16x8*)(wp + (size_t)(16 * nn + ln) * 256 + c0 + 8 * g);
#pragma unroll
    for (int ml = 0; ml < 4; ++ml)
#pragma unroll
      for (int nn = 0; nn < 3; ++nn)
        acc[ml][nn] = __builtin_amdgcn_mfma_f32_16x16x32_bf16(af[ml], bf[nn], acc[ml][nn], 0, 0, 0);
  }

  // bias
#pragma unroll
  for (int nn = 0; nn < 3; ++nn) {
    float bs = bias[head * 96 + wo * 48 + 16 * nn + ln];
#pragma unroll
    for (int ml = 0; ml < 4; ++ml)
#pragma unroll
      for (int r = 0; r < 4; ++r) acc[ml][nn][r] += bs;
  }

  __shared__ ushort tr[5120];
  const float QSC = 0.0625f * 1.44269504f;   // 1/sqrt(256) * log2(e)

  // rounds 0 (q, scaled), 1 (k): transpose to [l][d] (pad 40), write [bh][l][32]
  for (int rk = 0; rk < 2; ++rk) {
    float sc = rk ? 1.f : QSC;
    __syncthreads();
#pragma unroll
    for (int nn = 0; nn < 3; ++nn) {
      int ocl0 = wo * 48 + 16 * nn;
      if (ocl0 >= rk * 32 && ocl0 < rk * 32 + 32) {
        int d = ocl0 - rk * 32 + ln;
#pragma unroll
        for (int ml = 0; ml < 4; ++ml) {
          int lrow = wl * 64 + 16 * ml + 4 * g;
#pragma unroll
          for (int r = 0; r < 4; ++r)
            tr[(lrow + r) * 40 + d] = f2bf(acc[ml][nn][r] * sc);
        }
      }
    }
    __syncthreads();
    {
      int row = t >> 1, half = t & 1;
      uint4 v0 = *(const uint4*)&tr[row * 40 + half * 16];
      uint4 v1 = *(const uint4*)&tr[row * 40 + half * 16 + 8];
      ushort* dst = (rk ? kt : qt) +
                    ((size_t)bh * L_ + bx * 128 + row) * 32 + half * 16;
      *(uint4*)dst = v0;
      *(uint4*)(dst + 8) = v1;
    }
  }

  // round 2 (v): [d][l] (pad 136), PI-permute on global write
  __syncthreads();
  if (wo == 1) {
#pragma unroll
    for (int nn = 1; nn < 3; ++nn) {
      int d = 16 * (nn - 1) + ln;
#pragma unroll
      for (int ml = 0; ml < 4; ++ml) {
        int lc = wl * 64 + 16 * ml + 4 * g;
        union { ushort s[4]; uint2 u; } pk;
#pragma unroll
        for (int r = 0; r < 4; ++r) pk.s[r] = f2bf(acc[ml][nn][r]);
        *(uint2*)&tr[d * 136 + lc] = pk.u;
      }
    }
  }
  __syncthreads();
  {
    int d = t >> 3, s0 = t & 7;
    ushort* vdst = vb + ((size_t)bh * 32 + d) * L_ + bx * 128;
#pragma unroll
    for (int c = 0; c < 2; ++c) {
      int ch = s0 + 8 * c;
      int jj = ch >> 2, gg = ch & 3;
      uint2 lo = *(const uint2*)&tr[d * 136 + 32 * jj + 4 * gg];
      uint2 hi = *(const uint2*)&tr[d * 136 + 32 * jj + 16 + 4 * gg];
      *(uint4*)(vdst + 32 * jj + 8 * gg) = make_uint4(lo.x, lo.y, hi.x, hi.y);
    }
  }
}

// ---------------------------------------------------------------------------
// Kernel D: out pointwise conv via MFMA + residual (fp32 out).
// ---------------------------------------------------------------------------
template <int OCT>
__global__ __launch_bounds__(256) void pconv_mfma_kernel(
    const ushort* __restrict__ Xt, const ushort* __restrict__ Wb,
    const float* __restrict__ bias, const float* __restrict__ resid,
    float* __restrict__ out, int OC) {
  constexpr int NN = OCT / 16;
  int b = blockIdx.z;
  int t = threadIdx.x;
  int w = t >> 6, l = t & 63;
  int g = l >> 4, ln = l & 15;
  int wl = w >> 1, wo = w & 1;
  int lbase = blockIdx.x * 128 + wl * 64;
  int ocbase = blockIdx.y * (2 * OCT) + wo * OCT;

  const ushort* xp = Xt + ((size_t)b * L_ + lbase) * 256;
  const ushort* wp = Wb + (size_t)ocbase * 256;

  f32x4 acc[4][NN];
#pragma unroll
  for (int ml = 0; ml < 4; ++ml)
#pragma unroll
    for (int nn = 0; nn < NN; ++nn) acc[ml][nn] = (f32x4){0.f, 0.f, 0.f, 0.f};

  for (int c0 = 0; c0 < 256; c0 += 32) {
    bf16x8 af[4], bf[NN];
#pragma unroll
    for (int ml = 0; ml < 4; ++ml)
      af[ml] = *(const bf16x8*)(xp + (size_t)(16 * ml + ln) * 256 + c0 + 8 * g);
#pragma unroll
    for (int nn = 0; nn < NN; ++nn)
      bf[nn] = *(const bf16x8*)(wp + (size_t)(16 * nn + ln) * 256 + c0 + 8 * g);
#pragma unroll
    for (int ml = 0; ml < 4; ++ml)
#pragma unroll
      for (int nn = 0; nn < NN; ++nn)
        acc[ml][nn] = __builtin_amdgcn_mfma_f32_16x16x32_bf16(af[ml], bf[nn], acc[ml][nn], 0, 0, 0);
  }

#pragma unroll
  for (int nn = 0; nn < NN; ++nn) {
    int oc = ocbase + 16 * nn + ln;
    float bs = bias[oc];
#pragma unroll
    for (int ml = 0; ml < 4; ++ml) {
      int lr = lbase + 16 * ml + 4 * g;
      size_t ob = ((size_t)b * OC + oc) * L_ + lr;
      float4 rd = *(const float4*)(resid + ob);
      float4 st = make_float4(acc[ml][nn][0] + bs + rd.x, acc[ml][nn][1] + bs + rd.y,
                              acc[ml][nn][2] + bs + rd.z, acc[ml][nn][3] + bs + rd.w);
      *(float4*)(out + ob) = st;
    }
  }
}

// ---------------------------------------------------------------------------
// Kernel C: MFMA flash attention (round-7 structure), no max-subtraction.
// exp via raw v_exp_f32 builtin, but P-pack via PLAIN f2bf casts (no inline
// asm consumer of the trans result -> compiler inserts the TRANS wait-state).
// dbuf LDS staging, padded conflict-free layouts, XCD swizzle. grid 512.
// ---------------------------------------------------------------------------
__global__ __launch_bounds__(256) void attn_mfma_kernel(
    const ushort* __restrict__ qt, const ushort* __restrict__ kt,
    const ushort* __restrict__ vb, ushort* __restrict__ ot) {
  const int id = blockIdx.x;
  const int bh = ((id & 7) << 3) | (id >> 6);
  const int qtile = (id >> 3) & 7;
  const int b = bh >> 3, hh = bh & 7;
  const int t = threadIdx.x;
  const int w = t >> 6, l = t & 63;
  const int g = l >> 4, ln = l & 15;
  const int q0b = qtile * 128;
  const int q0 = q0b + w * 32;

  __shared__ ushort Kl[2][128 * 40];          // padded rows: 80B stride
  __shared__ ushort Vl[2][32 * 136];          // padded rows: 272B stride
  __shared__ __align__(16) ushort otile[128][40];

  const ushort* qbase = qt + (size_t)bh * (L_ * 32);
  const ushort* kbase = kt + (size_t)bh * (L_ * 32);
  const ushort* vbase = vb + (size_t)bh * (32 * L_);

  // staging geometry
  const int krow = t >> 1, khalf = t & 1;
  const ushort* kg = kbase + krow * 32 + khalf * 16;
  const int kwo = krow * 40 + khalf * 16;
  const int vrow = t >> 3, vc = (t & 7) * 16;
  const ushort* vg = vbase + (size_t)vrow * L_ + vc;
  const int vwo = vrow * 136 + vc;

  const f32x4 z4 = {0.f, 0.f, 0.f, 0.f};
  bf16x8 bq[2];
  bq[0] = *(const bf16x8*)(qbase + (size_t)(q0 + ln) * 32 + g * 8);
  bq[1] = *(const bf16x8*)(qbase + (size_t)(q0 + 16 + ln) * 32 + g * 8);

  union { ushort s[8]; bf16x8 v; } onesu;
#pragma unroll
  for (int i = 0; i < 8; ++i) onesu.s[i] = 0x3F80;  // bf16 1.0
  const bf16x8 ones = onesu.v;

  f32x4 oacc[2][2];  // [md][nq]
  oacc[0][0] = z4; oacc[0][1] = z4; oacc[1][0] = z4; oacc[1][1] = z4;
  f32x4 oaccS[2] = {z4, z4};

  // prologue: stage tile 0
  uint4 ka0, ka1, va0, va1;
  ka0 = *(const uint4*)kg;       ka1 = *(const uint4*)(kg + 8);
  va0 = *(const uint4*)vg;       va1 = *(const uint4*)(vg + 8);
  __builtin_amdgcn_sched_barrier(0);
  *(uint4*)&Kl[0][kwo] = ka0;    *(uint4*)&Kl[0][kwo + 8] = ka1;
  *(uint4*)&Vl[0][vwo] = va0;    *(uint4*)&Vl[0][vwo + 8] = va1;
  asm volatile("s_waitcnt lgkmcnt(0)" ::: "memory");
  __builtin_amdgcn_s_barrier();
  __builtin_amdgcn_sched_barrier(0);

  for (int tt = 0; tt < 8; ++tt) {
    const int cur = tt & 1;
    if (tt < 7) {
      ka0 = *(const uint4*)(kg + (tt + 1) * 4096);
      ka1 = *(const uint4*)(kg + (tt + 1) * 4096 + 8);
      va0 = *(const uint4*)(vg + (tt + 1) * 128);
      va1 = *(const uint4*)(vg + (tt + 1) * 128 + 8);
    }
    __builtin_amdgcn_sched_barrier(0);

    const ushort* Kc = &Kl[cur][0];
    const ushort* Vc = &Vl[cur][0];

    // QK^T  (S already in log2-units thanks to Q pre-scale)
    f32x4 sacc[8][2];
#pragma unroll
    for (int mk = 0; mk < 8; ++mk) {
      bf16x8 ak = *(const bf16x8*)(Kc + (16 * mk + ln) * 40 + g * 8);
      sacc[mk][0] = __builtin_amdgcn_mfma_f32_16x16x32_bf16(ak, bq[0], z4, 0, 0, 0);
      sacc[mk][1] = __builtin_amdgcn_mfma_f32_16x16x32_bf16(ak, bq[1], z4, 0, 0, 0);
    }

    // exp via raw v_exp_f32; pack via plain casts (compiler handles TRANS
    // hazard for its own consumers -- no inline asm in this dependency chain)
    uint upk[2][8][2];
#pragma unroll
    for (int nq = 0; nq < 2; ++nq) {
#pragma unroll
      for (int mk = 0; mk < 8; ++mk) {
        float e0 = __builtin_amdgcn_exp2f(sacc[mk][nq][0]);
        float e1 = __builtin_amdgcn_exp2f(sacc[mk][nq][1]);
        float e2 = __builtin_amdgcn_exp2f(sacc[mk][nq][2]);
        float e3 = __builtin_amdgcn_exp2f(sacc[mk][nq][3]);
        union { ushort s[4]; uint u[2]; } pk;
        pk.s[0] = f2bf(e0); pk.s[1] = f2bf(e1);
        pk.s[2] = f2bf(e2); pk.s[3] = f2bf(e3);
        upk[nq][mk][0] = pk.u[0]; upk[nq][mk][1] = pk.u[1];
      }
    }

    // PV + denominator
#pragma unroll
    for (int ks = 0; ks < 4; ++ks) {
      union { uint u[4]; bf16x8 v; } pb0, pb1;
      pb0.u[0] = upk[0][2 * ks][0]; pb0.u[1] = upk[0][2 * ks][1];
      pb0.u[2] = upk[0][2 * ks + 1][0]; pb0.u[3] = upk[0][2 * ks + 1][1];
      pb1.u[0] = upk[1][2 * ks][0]; pb1.u[1] = upk[1][2 * ks][1];
      pb1.u[2] = upk[1][2 * ks + 1][0]; pb1.u[3] = upk[1][2 * ks + 1][1];
      oaccS[0] = __builtin_amdgcn_mfma_f32_16x16x32_bf16(ones, pb0.v, oaccS[0], 0, 0, 0);
      oaccS[1] = __builtin_amdgcn_mfma_f32_16x16x32_bf16(ones, pb1.v, oaccS[1], 0, 0, 0);
#pragma unroll
      for (int md = 0; md < 2; ++md) {
        bf16x8 av = *(const bf16x8*)(Vc + (16 * md + ln) * 136 + 32 * ks + 8 * g);
        oacc[md][0] = __builtin_amdgcn_mfma_f32_16x16x32_bf16(av, pb0.v, oacc[md][0], 0, 0, 0);
        oacc[md][1] = __builtin_amdgcn_mfma_f32_16x16x32_bf16(av, pb1.v, oacc[md][1], 0, 0, 0);
      }
    }

    __builtin_amdgcn_sched_barrier(0);
    if (tt < 7) {
      const int nxt = cur ^ 1;
      *(uint4*)&Kl[nxt][kwo] = ka0;  *(uint4*)&Kl[nxt][kwo + 8] = ka1;
      *(uint4*)&Vl[nxt][vwo] = va0;  *(uint4*)&Vl[nxt][vwo + 8] = va1;
      asm volatile("s_waitcnt lgkmcnt(0)" ::: "memory");
      __builtin_amdgcn_s_barrier();
      __builtin_amdgcn_sched_barrier(0);
    }
  }

  // epilogue: normalize, LDS transpose, write ot[B][L][256]
  float rl0 = 1.f / oaccS[0][0];
  float rl1 = 1.f / oaccS[1][0];
#pragma unroll
  for (int md = 0; md < 2; ++md) {
    ushort4 p0, p1;
    p0.x = f2bf(oacc[md][0][0] * rl0); p0.y = f2bf(oacc[md][0][1] * rl0);
    p0.z = f2bf(oacc[md][0][2] * rl0); p0.w = f2bf(oacc[md][0][3] * rl0);
    p1.x = f2bf(oacc[md][1][0] * rl1); p1.y = f2bf(oacc[md][1][1] * rl1);
    p1.z = f2bf(oacc[md][1][2] * rl1); p1.w = f2bf(oacc[md][1][3] * rl1);
    *(ushort4*)&otile[w * 32 + ln][16 * md + 4 * g] = p0;
    *(ushort4*)&otile[w * 32 + 16 + ln][16 * md + 4 * g] = p1;
  }
  __syncthreads();
  {
    int row = t >> 1, half = t & 1;
    uint4 v0 = *(const uint4*)&otile[row][half * 16];
    uint4 v1 = *(const uint4*)&otile[row][half * 16 + 8];
    ushort* dstp = ot + ((size_t)(b * L_ + q0b + row)) * 256 + hh * 32 + half * 16;
    *(uint4*)dstp = v0;
    *(uint4*)(dstp + 8) = v1;
  }
}

// ---------------------------------------------------------------------------
extern "C" void kernel_launch(void* const* d_in, const int* in_sizes, int n_in,
                              void* d_out, int out_size, void* d_ws, size_t ws_size,
                              hipStream_t stream) {
  const float* x      = (const float*)d_in[0];
  const float* gamma  = (const float*)d_in[1];
  const float* beta   = (const float*)d_in[2];
  const float* dw     = (const float*)d_in[3];
  const float* qkv_w  = (const float*)d_in[4];
  const float* qkv_b  = (const float*)d_in[5];
  const float* out_w  = (const float*)d_in[6];
  const float* out_b  = (const float*)d_in[7];
  float* out = (float*)d_out;

  char* ws = (char*)d_ws;
  ushort* ht   = (ushort*)(ws);                   // 4 MiB @0  (dead after qkv)
  ushort* qtb  = (ushort*)(ws + (16u << 20));     // 4 MiB @16
  ushort* ktb  = (ushort*)(ws + (20u << 20));     // 4 MiB @20
  ushort* vbb  = (ushort*)(ws + (24u << 20));     // 4 MiB @24
  ushort* otb  = (ushort*)(ws);                   // 4 MiB @0  (reuse ht)
  ushort* wq   = (ushort*)(ws + (28u << 20));     // 384 KiB @28M
  ushort* wo   = (ushort*)(ws + (28u << 20) + (512u << 10));  // 128 KiB

  gnw_kernel<<<512, 256, 0, stream>>>(x, gamma, beta, dw,
                                      (const float4*)qkv_w, (const float4*)out_w,
                                      (uint2*)wq, (uint2*)wo, ht);
  qkv_fused_kernel<<<dim3(8, 8, B_), 256, 0, stream>>>(ht, wq, qkv_b, qtb, ktb, vbb);
  attn_mfma_kernel<<<512, 256, 0, stream>>>(qtb, ktb, vbb, otb);
  pconv_mfma_kernel<32><<<dim3(8, 4, B_), 256, 0, stream>>>(
      otb, wo, out_b, x, out, 256);
}

// Round 12
// 57.912 us; speedup vs baseline: 1.2142x; 1.0858x over previous
//
#include <hip/hip_runtime.h>
#include <hip/hip_bf16.h>

#define B_ 8
#define C_ 256
#define L_ 1024
#define NH_ 8
#define EPS_ 1e-5f

typedef __attribute__((ext_vector_type(8))) short bf16x8;
typedef __attribute__((ext_vector_type(4))) float f32x4;

static __device__ inline ushort f2bf(float f) {
  union { __hip_bfloat16 b; ushort u; } c;
  c.b = __float2bfloat16(f);
  return c.u;
}

// ---------------------------------------------------------------------------
// Kernel A: blocks 0-255: weight fp32->bf16 convert; blocks 256-511:
// GroupNorm + depthwise conv k=3. Output ht layout [B][32 cg][1024 l][8 c]
// (fully coalesced 1KB/wave stores; qkv reads it as contiguous fragments).
// ---------------------------------------------------------------------------
__global__ __launch_bounds__(256) void gnw_kernel(
    const float* __restrict__ x, const float* __restrict__ gamma,
    const float* __restrict__ beta, const float* __restrict__ dw,
    const float4* __restrict__ qw, const float4* __restrict__ ow,
    uint2* __restrict__ wq, uint2* __restrict__ wo_,
    ushort* __restrict__ ht) {
  __shared__ float hn[8 * L_];
  __shared__ float ws0[4], ws1[4];
  int t = threadIdx.x;
  if (blockIdx.x < 256) {
    int id = blockIdx.x * 256 + t;
    float4 v;
    uint2* dst;
    if (id < 49152) { v = qw[id]; dst = wq + id; }
    else { v = ow[id - 49152]; dst = wo_ + (id - 49152); }
    union { ushort s[4]; uint2 u; } p;
    p.s[0] = f2bf(v.x); p.s[1] = f2bf(v.y); p.s[2] = f2bf(v.z); p.s[3] = f2bf(v.w);
    *dst = p.u;
    return;
  }
  int blk = blockIdx.x - 256;     // b*32 + g
  int b = blk >> 5, g = blk & 31;
  const size_t base = ((size_t)(b * C_ + g * 8)) * L_;

  float s = 0.f, ss = 0.f;
  float vals[32];
#pragma unroll
  for (int i = 0; i < 32; ++i) {
    int e = t + 256 * i;
    float v = x[base + e];
    vals[i] = v;
    s += v; ss += v * v;
  }
#pragma unroll
  for (int off = 32; off >= 1; off >>= 1) {
    s  += __shfl_xor(s, off);
    ss += __shfl_xor(ss, off);
  }
  int wave = t >> 6;
  if ((t & 63) == 0) { ws0[wave] = s; ws1[wave] = ss; }
  __syncthreads();
  s  = ws0[0] + ws0[1] + ws0[2] + ws0[3];
  ss = ws1[0] + ws1[1] + ws1[2] + ws1[3];
  float mean = s * (1.f / 8192.f);
  float var = ss * (1.f / 8192.f) - mean * mean;
  float rstd = rsqrtf(var + EPS_);

#pragma unroll
  for (int i = 0; i < 32; ++i) {
    int e = t + 256 * i;
    int c = g * 8 + (e >> 10);
    float sc = gamma[c] * rstd;
    hn[e] = (vals[i] - mean) * sc + beta[c];
  }
  __syncthreads();
  float r[32];
#pragma unroll
  for (int i = 0; i < 32; ++i) {
    int e = t + 256 * i;
    int l = e & 1023;
    int c = g * 8 + (i >> 2);
    float w0 = dw[c * 3 + 0], w1 = dw[c * 3 + 1], w2 = dw[c * 3 + 2];
    float a = (l > 0) ? hn[e - 1] : 0.f;
    float m = hn[e];
    float z = (l < 1023) ? hn[e + 1] : 0.f;
    r[i] = w0 * a + w1 * m + w2 * z;
  }
#pragma unroll
  for (int li = 0; li < 4; ++li) {
    int l = t + 256 * li;
    union { ushort s8[8]; uint4 u; } pk;
#pragma unroll
    for (int cl = 0; cl < 8; ++cl) pk.s8[cl] = f2bf(r[4 * cl + li]);
    // ht[b][g][l][0..8): contiguous 16B/thread, 1KB/wave
    *(uint4*)(ht + (((size_t)(b * 32 + g)) * L_ + l) * 8) = pk.u;
  }
}

// ---------------------------------------------------------------------------
// Kernel B: qkv pointwise conv via MFMA, fused repack epilogue.
// Input ht [B][32][1024][8]. Q PRE-SCALED by 1/sqrt(C)*log2(e).
// ---------------------------------------------------------------------------
__global__ __launch_bounds__(256) void qkv_fused_kernel(
    const ushort* __restrict__ Xt, const ushort* __restrict__ Wb,
    const float* __restrict__ bias, ushort* __restrict__ qt,
    ushort* __restrict__ kt, ushort* __restrict__ vb) {
  int bx = blockIdx.x, head = blockIdx.y, b = blockIdx.z;
  int bh = b * 8 + head;
  int t = threadIdx.x;
  int w = t >> 6, l = t & 63;
  int g = l >> 4, ln = l & 15;
  int wl = w >> 1, wo = w & 1;
  int lbase = bx * 128 + wl * 64;

  const ushort* xb = Xt + (size_t)b * (32 * L_ * 8);
  const ushort* wp = Wb + (size_t)(head * 96 + wo * 48) * 256;

  f32x4 acc[4][3];
#pragma unroll
  for (int ml = 0; ml < 4; ++ml)
#pragma unroll
    for (int nn = 0; nn < 3; ++nn) acc[ml][nn] = (f32x4){0.f, 0.f, 0.f, 0.f};

  for (int c0 = 0; c0 < 256; c0 += 32) {
    bf16x8 af[4], bf[3];
#pragma unroll
    for (int ml = 0; ml < 4; ++ml)
      af[ml] = *(const bf16x8*)(xb +
          (((size_t)((c0 >> 3) + g)) * L_ + lbase + 16 * ml + ln) * 8);
#pragma unroll
    for (int nn = 0; nn < 3; ++nn)
      bf[nn] = *(const bf16x8*)(wp + (size_t)(16 * nn + ln) * 256 + c0 + 8 * g);
#pragma unroll
    for (int ml = 0; ml < 4; ++ml)
#pragma unroll
      for (int nn = 0; nn < 3; ++nn)
        acc[ml][nn] = __builtin_amdgcn_mfma_f32_16x16x32_bf16(af[ml], bf[nn], acc[ml][nn], 0, 0, 0);
  }

  // bias
#pragma unroll
  for (int nn = 0; nn < 3; ++nn) {
    float bs = bias[head * 96 + wo * 48 + 16 * nn + ln];
#pragma unroll
    for (int ml = 0; ml < 4; ++ml)
#pragma unroll
      for (int r = 0; r < 4; ++r) acc[ml][nn][r] += bs;
  }

  __shared__ ushort tr[5120];
  const float QSC = 0.0625f * 1.44269504f;   // 1/sqrt(256) * log2(e)

  // rounds 0 (q, scaled), 1 (k): transpose to [l][d] (pad 40), write [bh][l][32]
  for (int rk = 0; rk < 2; ++rk) {
    float sc = rk ? 1.f : QSC;
    __syncthreads();
#pragma unroll
    for (int nn = 0; nn < 3; ++nn) {
      int ocl0 = wo * 48 + 16 * nn;
      if (ocl0 >= rk * 32 && ocl0 < rk * 32 + 32) {
        int d = ocl0 - rk * 32 + ln;
#pragma unroll
        for (int ml = 0; ml < 4; ++ml) {
          int lrow = wl * 64 + 16 * ml + 4 * g;
#pragma unroll
          for (int r = 0; r < 4; ++r)
            tr[(lrow + r) * 40 + d] = f2bf(acc[ml][nn][r] * sc);
        }
      }
    }
    __syncthreads();
    {
      int row = t >> 1, half = t & 1;
      uint4 v0 = *(const uint4*)&tr[row * 40 + half * 16];
      uint4 v1 = *(const uint4*)&tr[row * 40 + half * 16 + 8];
      ushort* dst = (rk ? kt : qt) +
                    ((size_t)bh * L_ + bx * 128 + row) * 32 + half * 16;
      *(uint4*)dst = v0;
      *(uint4*)(dst + 8) = v1;
    }
  }

  // round 2 (v): [d][l] (pad 136), PI-permute on global write
  __syncthreads();
  if (wo == 1) {
#pragma unroll
    for (int nn = 1; nn < 3; ++nn) {
      int d = 16 * (nn - 1) + ln;
#pragma unroll
      for (int ml = 0; ml < 4; ++ml) {
        int lc = wl * 64 + 16 * ml + 4 * g;
        union { ushort s[4]; uint2 u; } pk;
#pragma unroll
        for (int r = 0; r < 4; ++r) pk.s[r] = f2bf(acc[ml][nn][r]);
        *(uint2*)&tr[d * 136 + lc] = pk.u;
      }
    }
  }
  __syncthreads();
  {
    int d = t >> 3, s0 = t & 7;
    ushort* vdst = vb + ((size_t)bh * 32 + d) * L_ + bx * 128;
#pragma unroll
    for (int c = 0; c < 2; ++c) {
      int ch = s0 + 8 * c;
      int jj = ch >> 2, gg = ch & 3;
      uint2 lo = *(const uint2*)&tr[d * 136 + 32 * jj + 4 * gg];
      uint2 hi = *(const uint2*)&tr[d * 136 + 32 * jj + 16 + 4 * gg];
      *(uint4*)(vdst + 32 * jj + 8 * gg) = make_uint4(lo.x, lo.y, hi.x, hi.y);
    }
  }
}

// ---------------------------------------------------------------------------
// Kernel D: out pointwise conv via MFMA + residual. Input ot [B][8][1024][32].
// Transposed epilogue through LDS -> coalesced fp32 writes + resid reads.
// Block = 128 l x 32 oc. grid (8, 8, B) = 512.
// ---------------------------------------------------------------------------
__global__ __launch_bounds__(256) void outconv_kernel(
    const ushort* __restrict__ Xt, const ushort* __restrict__ Wb,
    const float* __restrict__ bias, const float* __restrict__ resid,
    float* __restrict__ out) {
  int b = blockIdx.z;
  int t = threadIdx.x;
  int w = t >> 6, l = t & 63;
  int g = l >> 4, ln = l & 15;
  int wl = w >> 1, wo = w & 1;
  int lbase = blockIdx.x * 128 + wl * 64;
  int ocblk = blockIdx.y * 32;
  int ocbase = ocblk + wo * 16;

  const ushort* xb = Xt + (size_t)b * (8 * L_ * 32);
  const ushort* wp = Wb + (size_t)ocbase * 256;

  f32x4 acc[4];
#pragma unroll
  for (int ml = 0; ml < 4; ++ml) acc[ml] = (f32x4){0.f, 0.f, 0.f, 0.f};

  for (int c0 = 0; c0 < 256; c0 += 32) {
    bf16x8 af[4];
#pragma unroll
    for (int ml = 0; ml < 4; ++ml)
      af[ml] = *(const bf16x8*)(xb +
          ((size_t)(c0 >> 5) * L_ + lbase + 16 * ml + ln) * 32 + 8 * g);
    bf16x8 bf = *(const bf16x8*)(wp + (size_t)ln * 256 + c0 + 8 * g);
#pragma unroll
    for (int ml = 0; ml < 4; ++ml)
      acc[ml] = __builtin_amdgcn_mfma_f32_16x16x32_bf16(af[ml], bf, acc[ml], 0, 0, 0);
  }

  __shared__ float tile[32][132];
  float bs = bias[ocbase + ln];
#pragma unroll
  for (int ml = 0; ml < 4; ++ml) {
    int ll = wl * 64 + 16 * ml + 4 * g;
    float4 v = make_float4(acc[ml][0] + bs, acc[ml][1] + bs,
                           acc[ml][2] + bs, acc[ml][3] + bs);
    *(float4*)&tile[wo * 16 + ln][ll] = v;
  }
  __syncthreads();
  {
    int ocl = t >> 3, lq = t & 7;           // 32 oc x 8 l-chunks of 16
    const float* src = &tile[ocl][lq * 16];
    size_t ob = ((size_t)b * 256 + ocblk + ocl) * L_ + blockIdx.x * 128 + lq * 16;
#pragma unroll
    for (int i = 0; i < 4; ++i) {
      float4 v = *(const float4*)(src + 4 * i);
      float4 rd = *(const float4*)(resid + ob + 4 * i);
      v.x += rd.x; v.y += rd.y; v.z += rd.z; v.w += rd.w;
      *(float4*)(out + ob + 4 * i) = v;
    }
  }
}

// ---------------------------------------------------------------------------
// Kernel C: MFMA flash attention (round-11 math), LDS overlay: otile reuses
// K buffer 0 region (dead after tt=6 barrier) -> 37,888B -> 4 blocks/CU.
// Output ot[bh][l][32] (contiguous 8KB/block epilogue store). grid 512.
// ---------------------------------------------------------------------------
__global__ __launch_bounds__(256) void attn_mfma_kernel(
    const ushort* __restrict__ qt, const ushort* __restrict__ kt,
    const ushort* __restrict__ vb, ushort* __restrict__ ot) {
  const int id = blockIdx.x;
  const int bh = ((id & 7) << 3) | (id >> 6);
  const int qtile = (id >> 3) & 7;
  const int t = threadIdx.x;
  const int w = t >> 6, l = t & 63;
  const int g = l >> 4, ln = l & 15;
  const int q0b = qtile * 128;
  const int q0 = q0b + w * 32;

  // smem (ushorts): K0 @0 (5120), K1 @5120, V0 @10240 (4352), V1 @14592.
  // otile [128][40] = 5120 overlays K0 exactly (dead in tt=7 / epilogue).
  __shared__ __align__(16) ushort smem[18944];   // 37,888 B

  const ushort* qbase = qt + (size_t)bh * (L_ * 32);
  const ushort* kbase = kt + (size_t)bh * (L_ * 32);
  const ushort* vbase = vb + (size_t)bh * (32 * L_);

  // staging geometry
  const int krow = t >> 1, khalf = t & 1;
  const ushort* kg = kbase + krow * 32 + khalf * 16;
  const int kwo = krow * 40 + khalf * 16;
  const int vrow = t >> 3, vc = (t & 7) * 16;
  const ushort* vg = vbase + (size_t)vrow * L_ + vc;
  const int vwo = vrow * 136 + vc;

  const f32x4 z4 = {0.f, 0.f, 0.f, 0.f};
  bf16x8 bq[2];
  bq[0] = *(const bf16x8*)(qbase + (size_t)(q0 + ln) * 32 + g * 8);
  bq[1] = *(const bf16x8*)(qbase + (size_t)(q0 + 16 + ln) * 32 + g * 8);

  union { ushort s[8]; bf16x8 v; } onesu;
#pragma unroll
  for (int i = 0; i < 8; ++i) onesu.s[i] = 0x3F80;  // bf16 1.0
  const bf16x8 ones = onesu.v;

  f32x4 oacc[2][2];  // [md][nq]
  oacc[0][0] = z4; oacc[0][1] = z4; oacc[1][0] = z4; oacc[1][1] = z4;
  f32x4 oaccS[2] = {z4, z4};

  // prologue: stage tile 0
  uint4 ka0, ka1, va0, va1;
  ka0 = *(const uint4*)kg;       ka1 = *(const uint4*)(kg + 8);
  va0 = *(const uint4*)vg;       va1 = *(const uint4*)(vg + 8);
  __builtin_amdgcn_sched_barrier(0);
  *(uint4*)&smem[kwo] = ka0;             *(uint4*)&smem[kwo + 8] = ka1;
  *(uint4*)&smem[10240 + vwo] = va0;     *(uint4*)&smem[10240 + vwo + 8] = va1;
  asm volatile("s_waitcnt lgkmcnt(0)" ::: "memory");
  __builtin_amdgcn_s_barrier();
  __builtin_amdgcn_sched_barrier(0);

  for (int tt = 0; tt < 8; ++tt) {
    const int cur = tt & 1;
    if (tt < 7) {
      ka0 = *(const uint4*)(kg + (tt + 1) * 4096);
      ka1 = *(const uint4*)(kg + (tt + 1) * 4096 + 8);
      va0 = *(const uint4*)(vg + (tt + 1) * 128);
      va1 = *(const uint4*)(vg + (tt + 1) * 128 + 8);
    }
    __builtin_amdgcn_sched_barrier(0);

    const ushort* Kc = &smem[cur * 5120];
    const ushort* Vc = &smem[10240 + cur * 4352];

    // QK^T  (S already in log2-units thanks to Q pre-scale)
    f32x4 sacc[8][2];
#pragma unroll
    for (int mk = 0; mk < 8; ++mk) {
      bf16x8 ak = *(const bf16x8*)(Kc + (16 * mk + ln) * 40 + g * 8);
      sacc[mk][0] = __builtin_amdgcn_mfma_f32_16x16x32_bf16(ak, bq[0], z4, 0, 0, 0);
      sacc[mk][1] = __builtin_amdgcn_mfma_f32_16x16x32_bf16(ak, bq[1], z4, 0, 0, 0);
    }

    // exp via raw v_exp_f32; pack via plain casts (no inline asm consumes
    // the TRANS result -- rounds 9/10 lesson)
    uint upk[2][8][2];
#pragma unroll
    for (int nq = 0; nq < 2; ++nq) {
#pragma unroll
      for (int mk = 0; mk < 8; ++mk) {
        float e0 = __builtin_amdgcn_exp2f(sacc[mk][nq][0]);
        float e1 = __builtin_amdgcn_exp2f(sacc[mk][nq][1]);
        float e2 = __builtin_amdgcn_exp2f(sacc[mk][nq][2]);
        float e3 = __builtin_amdgcn_exp2f(sacc[mk][nq][3]);
        union { ushort s[4]; uint u[2]; } pk;
        pk.s[0] = f2bf(e0); pk.s[1] = f2bf(e1);
        pk.s[2] = f2bf(e2); pk.s[3] = f2bf(e3);
        upk[nq][mk][0] = pk.u[0]; upk[nq][mk][1] = pk.u[1];
      }
    }

    // PV + denominator
#pragma unroll
    for (int ks = 0; ks < 4; ++ks) {
      union { uint u[4]; bf16x8 v; } pb0, pb1;
      pb0.u[0] = upk[0][2 * ks][0]; pb0.u[1] = upk[0][2 * ks][1];
      pb0.u[2] = upk[0][2 * ks + 1][0]; pb0.u[3] = upk[0][2 * ks + 1][1];
      pb1.u[0] = upk[1][2 * ks][0]; pb1.u[1] = upk[1][2 * ks][1];
      pb1.u[2] = upk[1][2 * ks + 1][0]; pb1.u[3] = upk[1][2 * ks + 1][1];
      oaccS[0] = __builtin_amdgcn_mfma_f32_16x16x32_bf16(ones, pb0.v, oaccS[0], 0, 0, 0);
      oaccS[1] = __builtin_amdgcn_mfma_f32_16x16x32_bf16(ones, pb1.v, oaccS[1], 0, 0, 0);
#pragma unroll
      for (int md = 0; md < 2; ++md) {
        bf16x8 av = *(const bf16x8*)(Vc + (16 * md + ln) * 136 + 32 * ks + 8 * g);
        oacc[md][0] = __builtin_amdgcn_mfma_f32_16x16x32_bf16(av, pb0.v, oacc[md][0], 0, 0, 0);
        oacc[md][1] = __builtin_amdgcn_mfma_f32_16x16x32_bf16(av, pb1.v, oacc[md][1], 0, 0, 0);
      }
    }

    __builtin_amdgcn_sched_barrier(0);
    if (tt < 7) {
      const int nxt = cur ^ 1;
      *(uint4*)&smem[nxt * 5120 + kwo] = ka0;
      *(uint4*)&smem[nxt * 5120 + kwo + 8] = ka1;
      *(uint4*)&smem[10240 + nxt * 4352 + vwo] = va0;
      *(uint4*)&smem[10240 + nxt * 4352 + vwo + 8] = va1;
      asm volatile("s_waitcnt lgkmcnt(0)" ::: "memory");
      __builtin_amdgcn_s_barrier();
      __builtin_amdgcn_sched_barrier(0);
    }
  }

  // epilogue: normalize, LDS transpose (otile overlays K0), write ot[bh][l][32]
  ushort* otile = &smem[0];   // [128][40]
  float rl0 = 1.f / oaccS[0][0];
  float rl1 = 1.f / oaccS[1][0];
#pragma unroll
  for (int md = 0; md < 2; ++md) {
    ushort4 p0, p1;
    p0.x = f2bf(oacc[md][0][0] * rl0); p0.y = f2bf(oacc[md][0][1] * rl0);
    p0.z = f2bf(oacc[md][0][2] * rl0); p0.w = f2bf(oacc[md][0][3] * rl0);
    p1.x = f2bf(oacc[md][1][0] * rl1); p1.y = f2bf(oacc[md][1][1] * rl1);
    p1.z = f2bf(oacc[md][1][2] * rl1); p1.w = f2bf(oacc[md][1][3] * rl1);
    *(ushort4*)&otile[(w * 32 + ln) * 40 + 16 * md + 4 * g] = p0;
    *(ushort4*)&otile[(w * 32 + 16 + ln) * 40 + 16 * md + 4 * g] = p1;
  }
  __syncthreads();
  {
    int row = t >> 1, half = t & 1;
    uint4 v0 = *(const uint4*)&otile[row * 40 + half * 16];
    uint4 v1 = *(const uint4*)&otile[row * 40 + half * 16 + 8];
    ushort* dstp = ot + ((size_t)bh * L_ + q0b + row) * 32 + half * 16;
    *(uint4*)dstp = v0;
    *(uint4*)(dstp + 8) = v1;
  }
}

// ---------------------------------------------------------------------------
extern "C" void kernel_launch(void* const* d_in, const int* in_sizes, int n_in,
                              void* d_out, int out_size, void* d_ws, size_t ws_size,
                              hipStream_t stream) {
  const float* x      = (const float*)d_in[0];
  const float* gamma  = (const float*)d_in[1];
  const float* beta   = (const float*)d_in[2];
  const float* dw     = (const float*)d_in[3];
  const float* qkv_w  = (const float*)d_in[4];
  const float* qkv_b  = (const float*)d_in[5];
  const float* out_w  = (const float*)d_in[6];
  const float* out_b  = (const float*)d_in[7];
  float* out = (float*)d_out;

  char* ws = (char*)d_ws;
  ushort* ht   = (ushort*)(ws);                   // 4 MiB @0  (dead after qkv)
  ushort* qtb  = (ushort*)(ws + (16u << 20));     // 4 MiB @16
  ushort* ktb  = (ushort*)(ws + (20u << 20));     // 4 MiB @20
  ushort* vbb  = (ushort*)(ws + (24u << 20));     // 4 MiB @24
  ushort* otb  = (ushort*)(ws);                   // 4 MiB @0  (reuse ht)
  ushort* wq   = (ushort*)(ws + (28u << 20));     // 384 KiB @28M
  ushort* wo   = (ushort*)(ws + (28u << 20) + (512u << 10));  // 128 KiB

  gnw_kernel<<<512, 256, 0, stream>>>(x, gamma, beta, dw,
                                      (const float4*)qkv_w, (const float4*)out_w,
                                      (uint2*)wq, (uint2*)wo, ht);
  qkv_fused_kernel<<<dim3(8, 8, B_), 256, 0, stream>>>(ht, wq, qkv_b, qtb, ktb, vbb);
  attn_mfma_kernel<<<512, 256, 0, stream>>>(qtb, ktb, vbb, otb);
  outconv_kernel<<<dim3(8, 8, B_), 256, 0, stream>>>(otb, wo, out_b, x, out);
}

// Round 14
// 54.964 us; speedup vs baseline: 1.2793x; 1.0536x over previous
//
#include <hip/hip_runtime.h>
#include <hip/hip_bf16.h>

#define B_ 8
#define C_ 256
#define L_ 1024
#define NH_ 8
#define EPS_ 1e-5f

typedef __attribute__((ext_vector_type(8))) _Float16 half8;
typedef __attribute__((ext_vector_type(2))) __fp16 fp16x2;
typedef __attribute__((ext_vector_type(4))) float f32x4;

static __device__ inline ushort f2h(float f) {
  union { _Float16 h; ushort u; } c;
  c.h = (_Float16)f;
  return c.u;
}

// pack two fp32 -> fp16 pair via v_cvt_pkrtz_f16_f32 (compiler builtin --
// safe on TRANS-result inputs, unlike inline asm; rounds 9-11 lesson)
static __device__ inline uint pkh(float a, float b) {
  union { fp16x2 v; uint u; } c;
  c.v = __builtin_amdgcn_cvt_pkrtz(a, b);
  return c.u;
}

// ---------------------------------------------------------------------------
// Kernel A: blocks 0-255: weight fp32->fp16 convert; blocks 256-511:
// GroupNorm + depthwise conv k=3. Output ht layout [B][32 cg][1024 l][8 c].
// ---------------------------------------------------------------------------
__global__ __launch_bounds__(256) void gnw_kernel(
    const float* __restrict__ x, const float* __restrict__ gamma,
    const float* __restrict__ beta, const float* __restrict__ dw,
    const float4* __restrict__ qw, const float4* __restrict__ ow,
    uint2* __restrict__ wq, uint2* __restrict__ wo_,
    ushort* __restrict__ ht) {
  __shared__ float hn[8 * L_];
  __shared__ float ws0[4], ws1[4];
  int t = threadIdx.x;
  if (blockIdx.x < 256) {
    int id = blockIdx.x * 256 + t;
    float4 v;
    uint2* dst;
    if (id < 49152) { v = qw[id]; dst = wq + id; }
    else { v = ow[id - 49152]; dst = wo_ + (id - 49152); }
    *dst = make_uint2(pkh(v.x, v.y), pkh(v.z, v.w));
    return;
  }
  int blk = blockIdx.x - 256;     // b*32 + g
  int b = blk >> 5, g = blk & 31;
  const size_t base = ((size_t)(b * C_ + g * 8)) * L_;

  float s = 0.f, ss = 0.f;
  float vals[32];
#pragma unroll
  for (int i = 0; i < 32; ++i) {
    int e = t + 256 * i;
    float v = x[base + e];
    vals[i] = v;
    s += v; ss += v * v;
  }
#pragma unroll
  for (int off = 32; off >= 1; off >>= 1) {
    s  += __shfl_xor(s, off);
    ss += __shfl_xor(ss, off);
  }
  int wave = t >> 6;
  if ((t & 63) == 0) { ws0[wave] = s; ws1[wave] = ss; }
  __syncthreads();
  s  = ws0[0] + ws0[1] + ws0[2] + ws0[3];
  ss = ws1[0] + ws1[1] + ws1[2] + ws1[3];
  float mean = s * (1.f / 8192.f);
  float var = ss * (1.f / 8192.f) - mean * mean;
  float rstd = rsqrtf(var + EPS_);

#pragma unroll
  for (int i = 0; i < 32; ++i) {
    int e = t + 256 * i;
    int c = g * 8 + (e >> 10);
    float sc = gamma[c] * rstd;
    hn[e] = (vals[i] - mean) * sc + beta[c];
  }
  __syncthreads();
  float r[32];
#pragma unroll
  for (int i = 0; i < 32; ++i) {
    int e = t + 256 * i;
    int l = e & 1023;
    int c = g * 8 + (i >> 2);
    float w0 = dw[c * 3 + 0], w1 = dw[c * 3 + 1], w2 = dw[c * 3 + 2];
    float a = (l > 0) ? hn[e - 1] : 0.f;
    float m = hn[e];
    float z = (l < 1023) ? hn[e + 1] : 0.f;
    r[i] = w0 * a + w1 * m + w2 * z;
  }
#pragma unroll
  for (int li = 0; li < 4; ++li) {
    int l = t + 256 * li;
    uint4 pk;
    pk.x = pkh(r[0 + li],  r[4 + li]);
    pk.y = pkh(r[8 + li],  r[12 + li]);
    pk.z = pkh(r[16 + li], r[20 + li]);
    pk.w = pkh(r[24 + li], r[28 + li]);
    *(uint4*)(ht + (((size_t)(b * 32 + g)) * L_ + l) * 8) = pk;
  }
}

// ---------------------------------------------------------------------------
// Kernel B: qkv pointwise conv via MFMA (fp16), fused repack epilogue.
// Input ht [B][32][1024][8]. Q PRE-SCALED by 1/sqrt(C)*log2(e).
// ---------------------------------------------------------------------------
__global__ __launch_bounds__(256) void qkv_fused_kernel(
    const ushort* __restrict__ Xt, const ushort* __restrict__ Wb,
    const float* __restrict__ bias, ushort* __restrict__ qt,
    ushort* __restrict__ kt, ushort* __restrict__ vb) {
  int bx = blockIdx.x, head = blockIdx.y, b = blockIdx.z;
  int bh = b * 8 + head;
  int t = threadIdx.x;
  int w = t >> 6, l = t & 63;
  int g = l >> 4, ln = l & 15;
  int wl = w >> 1, wo = w & 1;
  int lbase = bx * 128 + wl * 64;

  const ushort* xb = Xt + (size_t)b * (32 * L_ * 8);
  const ushort* wp = Wb + (size_t)(head * 96 + wo * 48) * 256;

  f32x4 acc[4][3];
#pragma unroll
  for (int ml = 0; ml < 4; ++ml)
#pragma unroll
    for (int nn = 0; nn < 3; ++nn) acc[ml][nn] = (f32x4){0.f, 0.f, 0.f, 0.f};

  for (int c0 = 0; c0 < 256; c0 += 32) {
    half8 af[4], bf[3];
#pragma unroll
    for (int ml = 0; ml < 4; ++ml)
      af[ml] = *(const half8*)(xb +
          (((size_t)((c0 >> 3) + g)) * L_ + lbase + 16 * ml + ln) * 8);
#pragma unroll
    for (int nn = 0; nn < 3; ++nn)
      bf[nn] = *(const half8*)(wp + (size_t)(16 * nn + ln) * 256 + c0 + 8 * g);
#pragma unroll
    for (int ml = 0; ml < 4; ++ml)
#pragma unroll
      for (int nn = 0; nn < 3; ++nn)
        acc[ml][nn] = __builtin_amdgcn_mfma_f32_16x16x32_f16(af[ml], bf[nn], acc[ml][nn], 0, 0, 0);
  }

  // bias
#pragma unroll
  for (int nn = 0; nn < 3; ++nn) {
    float bs = bias[head * 96 + wo * 48 + 16 * nn + ln];
#pragma unroll
    for (int ml = 0; ml < 4; ++ml)
#pragma unroll
      for (int r = 0; r < 4; ++r) acc[ml][nn][r] += bs;
  }

  __shared__ ushort tr[5120];
  const float QSC = 0.0625f * 1.44269504f;   // 1/sqrt(256) * log2(e)

  // rounds 0 (q, scaled), 1 (k): transpose to [l][d] (pad 40), write [bh][l][32]
  for (int rk = 0; rk < 2; ++rk) {
    float sc = rk ? 1.f : QSC;
    __syncthreads();
#pragma unroll
    for (int nn = 0; nn < 3; ++nn) {
      int ocl0 = wo * 48 + 16 * nn;
      if (ocl0 >= rk * 32 && ocl0 < rk * 32 + 32) {
        int d = ocl0 - rk * 32 + ln;
#pragma unroll
        for (int ml = 0; ml < 4; ++ml) {
          int lrow = wl * 64 + 16 * ml + 4 * g;
#pragma unroll
          for (int r = 0; r < 4; ++r)
            tr[(lrow + r) * 40 + d] = f2h(acc[ml][nn][r] * sc);
        }
      }
    }
    __syncthreads();
    {
      int row = t >> 1, half = t & 1;
      uint4 v0 = *(const uint4*)&tr[row * 40 + half * 16];
      uint4 v1 = *(const uint4*)&tr[row * 40 + half * 16 + 8];
      ushort* dst = (rk ? kt : qt) +
                    ((size_t)bh * L_ + bx * 128 + row) * 32 + half * 16;
      *(uint4*)dst = v0;
      *(uint4*)(dst + 8) = v1;
    }
  }

  // round 2 (v): [d][l] (pad 136), PI-permute on global write
  __syncthreads();
  if (wo == 1) {
#pragma unroll
    for (int nn = 1; nn < 3; ++nn) {
      int d = 16 * (nn - 1) + ln;
#pragma unroll
      for (int ml = 0; ml < 4; ++ml) {
        int lc = wl * 64 + 16 * ml + 4 * g;
        *(uint2*)&tr[d * 136 + lc] =
            make_uint2(pkh(acc[ml][nn][0], acc[ml][nn][1]),
                       pkh(acc[ml][nn][2], acc[ml][nn][3]));
      }
    }
  }
  __syncthreads();
  {
    int d = t >> 3, s0 = t & 7;
    ushort* vdst = vb + ((size_t)bh * 32 + d) * L_ + bx * 128;
#pragma unroll
    for (int c = 0; c < 2; ++c) {
      int ch = s0 + 8 * c;
      int jj = ch >> 2, gg = ch & 3;
      uint2 lo = *(const uint2*)&tr[d * 136 + 32 * jj + 4 * gg];
      uint2 hi = *(const uint2*)&tr[d * 136 + 32 * jj + 16 + 4 * gg];
      *(uint4*)(vdst + 32 * jj + 8 * gg) = make_uint4(lo.x, lo.y, hi.x, hi.y);
    }
  }
}

// ---------------------------------------------------------------------------
// Kernel D: out pointwise conv via MFMA (fp16) + residual. Input ot
// [bh][1024][32] fp16. Transposed epilogue through LDS. grid (8, 8, B).
// ---------------------------------------------------------------------------
__global__ __launch_bounds__(256) void outconv_kernel(
    const ushort* __restrict__ Xt, const ushort* __restrict__ Wb,
    const float* __restrict__ bias, const float* __restrict__ resid,
    float* __restrict__ out) {
  int b = blockIdx.z;
  int t = threadIdx.x;
  int w = t >> 6, l = t & 63;
  int g = l >> 4, ln = l & 15;
  int wl = w >> 1, wo = w & 1;
  int lbase = blockIdx.x * 128 + wl * 64;
  int ocblk = blockIdx.y * 32;
  int ocbase = ocblk + wo * 16;

  const ushort* xb = Xt + (size_t)b * (8 * L_ * 32);
  const ushort* wp = Wb + (size_t)ocbase * 256;

  f32x4 acc[4];
#pragma unroll
  for (int ml = 0; ml < 4; ++ml) acc[ml] = (f32x4){0.f, 0.f, 0.f, 0.f};

  for (int c0 = 0; c0 < 256; c0 += 32) {
    half8 af[4];
#pragma unroll
    for (int ml = 0; ml < 4; ++ml)
      af[ml] = *(const half8*)(xb +
          ((size_t)(c0 >> 5) * L_ + lbase + 16 * ml + ln) * 32 + 8 * g);
    half8 bf = *(const half8*)(wp + (size_t)ln * 256 + c0 + 8 * g);
#pragma unroll
    for (int ml = 0; ml < 4; ++ml)
      acc[ml] = __builtin_amdgcn_mfma_f32_16x16x32_f16(af[ml], bf, acc[ml], 0, 0, 0);
  }

  __shared__ float tile[32][132];
  float bs = bias[ocbase + ln];
#pragma unroll
  for (int ml = 0; ml < 4; ++ml) {
    int ll = wl * 64 + 16 * ml + 4 * g;
    float4 v = make_float4(acc[ml][0] + bs, acc[ml][1] + bs,
                           acc[ml][2] + bs, acc[ml][3] + bs);
    *(float4*)&tile[wo * 16 + ln][ll] = v;
  }
  __syncthreads();
  {
    int ocl = t >> 3, lq = t & 7;           // 32 oc x 8 l-chunks of 16
    const float* src = &tile[ocl][lq * 16];
    size_t ob = ((size_t)b * 256 + ocblk + ocl) * L_ + blockIdx.x * 128 + lq * 16;
#pragma unroll
    for (int i = 0; i < 4; ++i) {
      float4 v = *(const float4*)(src + 4 * i);
      float4 rd = *(const float4*)(resid + ob + 4 * i);
      v.x += rd.x; v.y += rd.y; v.z += rd.z; v.w += rd.w;
      *(float4*)(out + ob + 4 * i) = v;
    }
  }
}

// ---------------------------------------------------------------------------
// Kernel C: MFMA flash attention (fp16 pipeline), no max-subtraction.
// exp via v_exp_f32 builtin; P-pack via cvt_pkrtz builtin (1 op / 2 elems).
// dbuf LDS staging, padded layouts, otile overlays K0. grid 512, 4 blk/CU.
// ---------------------------------------------------------------------------
__global__ __launch_bounds__(256) void attn_mfma_kernel(
    const ushort* __restrict__ qt, const ushort* __restrict__ kt,
    const ushort* __restrict__ vb, ushort* __restrict__ ot) {
  const int id = blockIdx.x;
  const int bh = ((id & 7) << 3) | (id >> 6);
  const int qtile = (id >> 3) & 7;
  const int t = threadIdx.x;
  const int w = t >> 6, l = t & 63;
  const int g = l >> 4, ln = l & 15;
  const int q0b = qtile * 128;
  const int q0 = q0b + w * 32;

  // smem (ushorts): K0 @0 (5120), K1 @5120, V0 @10240 (4352), V1 @14592.
  // otile [128][40] = 5120 overlays K0 (dead in tt=7 / epilogue).
  __shared__ __align__(16) ushort smem[18944];   // 37,888 B

  const ushort* qbase = qt + (size_t)bh * (L_ * 32);
  const ushort* kbase = kt + (size_t)bh * (L_ * 32);
  const ushort* vbase = vb + (size_t)bh * (32 * L_);

  // staging geometry
  const int krow = t >> 1, khalf = t & 1;
  const ushort* kg = kbase + krow * 32 + khalf * 16;
  const int kwo = krow * 40 + khalf * 16;
  const int vrow = t >> 3, vc = (t & 7) * 16;
  const ushort* vg = vbase + (size_t)vrow * L_ + vc;
  const int vwo = vrow * 136 + vc;

  const f32x4 z4 = {0.f, 0.f, 0.f, 0.f};
  half8 bq[2];
  bq[0] = *(const half8*)(qbase + (size_t)(q0 + ln) * 32 + g * 8);
  bq[1] = *(const half8*)(qbase + (size_t)(q0 + 16 + ln) * 32 + g * 8);

  union { ushort s[8]; half8 v; } onesu;
#pragma unroll
  for (int i = 0; i < 8; ++i) onesu.s[i] = 0x3C00;  // fp16 1.0
  const half8 ones = onesu.v;

  f32x4 oacc[2][2];  // [md][nq]
  oacc[0][0] = z4; oacc[0][1] = z4; oacc[1][0] = z4; oacc[1][1] = z4;
  f32x4 oaccS[2] = {z4, z4};

  // prologue: stage tile 0
  uint4 ka0, ka1, va0, va1;
  ka0 = *(const uint4*)kg;       ka1 = *(const uint4*)(kg + 8);
  va0 = *(const uint4*)vg;       va1 = *(const uint4*)(vg + 8);
  __builtin_amdgcn_sched_barrier(0);
  *(uint4*)&smem[kwo] = ka0;             *(uint4*)&smem[kwo + 8] = ka1;
  *(uint4*)&smem[10240 + vwo] = va0;     *(uint4*)&smem[10240 + vwo + 8] = va1;
  asm volatile("s_waitcnt lgkmcnt(0)" ::: "memory");
  __builtin_amdgcn_s_barrier();
  __builtin_amdgcn_sched_barrier(0);

  for (int tt = 0; tt < 8; ++tt) {
    const int cur = tt & 1;
    if (tt < 7) {
      ka0 = *(const uint4*)(kg + (tt + 1) * 4096);
      ka1 = *(const uint4*)(kg + (tt + 1) * 4096 + 8);
      va0 = *(const uint4*)(vg + (tt + 1) * 128);
      va1 = *(const uint4*)(vg + (tt + 1) * 128 + 8);
    }
    __builtin_amdgcn_sched_barrier(0);

    const ushort* Kc = &smem[cur * 5120];
    const ushort* Vc = &smem[10240 + cur * 4352];

    // QK^T  (S already in log2-units thanks to Q pre-scale)
    f32x4 sacc[8][2];
#pragma unroll
    for (int mk = 0; mk < 8; ++mk) {
      half8 ak = *(const half8*)(Kc + (16 * mk + ln) * 40 + g * 8);
      sacc[mk][0] = __builtin_amdgcn_mfma_f32_16x16x32_f16(ak, bq[0], z4, 0, 0, 0);
      sacc[mk][1] = __builtin_amdgcn_mfma_f32_16x16x32_f16(ak, bq[1], z4, 0, 0, 0);
    }

    // exp via v_exp_f32; pack pairs via cvt_pkrtz (compiler builtin -- safe
    // TRANS consumer, 1 op per 2 elems)
    uint upk[2][8][2];
#pragma unroll
    for (int nq = 0; nq < 2; ++nq) {
#pragma unroll
      for (int mk = 0; mk < 8; ++mk) {
        float e0 = __builtin_amdgcn_exp2f(sacc[mk][nq][0]);
        float e1 = __builtin_amdgcn_exp2f(sacc[mk][nq][1]);
        float e2 = __builtin_amdgcn_exp2f(sacc[mk][nq][2]);
        float e3 = __builtin_amdgcn_exp2f(sacc[mk][nq][3]);
        upk[nq][mk][0] = pkh(e0, e1);
        upk[nq][mk][1] = pkh(e2, e3);
      }
    }

    // PV + denominator
#pragma unroll
    for (int ks = 0; ks < 4; ++ks) {
      union { uint u[4]; half8 v; } pb0, pb1;
      pb0.u[0] = upk[0][2 * ks][0]; pb0.u[1] = upk[0][2 * ks][1];
      pb0.u[2] = upk[0][2 * ks + 1][0]; pb0.u[3] = upk[0][2 * ks + 1][1];
      pb1.u[0] = upk[1][2 * ks][0]; pb1.u[1] = upk[1][2 * ks][1];
      pb1.u[2] = upk[1][2 * ks + 1][0]; pb1.u[3] = upk[1][2 * ks + 1][1];
      oaccS[0] = __builtin_amdgcn_mfma_f32_16x16x32_f16(ones, pb0.v, oaccS[0], 0, 0, 0);
      oaccS[1] = __builtin_amdgcn_mfma_f32_16x16x32_f16(ones, pb1.v, oaccS[1], 0, 0, 0);
#pragma unroll
      for (int md = 0; md < 2; ++md) {
        half8 av = *(const half8*)(Vc + (16 * md + ln) * 136 + 32 * ks + 8 * g);
        oacc[md][0] = __builtin_amdgcn_mfma_f32_16x16x32_f16(av, pb0.v, oacc[md][0], 0, 0, 0);
        oacc[md][1] = __builtin_amdgcn_mfma_f32_16x16x32_f16(av, pb1.v, oacc[md][1], 0, 0, 0);
      }
    }

    __builtin_amdgcn_sched_barrier(0);
    if (tt < 7) {
      const int nxt = cur ^ 1;
      *(uint4*)&smem[nxt * 5120 + kwo] = ka0;
      *(uint4*)&smem[nxt * 5120 + kwo + 8] = ka1;
      *(uint4*)&smem[10240 + nxt * 4352 + vwo] = va0;
      *(uint4*)&smem[10240 + nxt * 4352 + vwo + 8] = va1;
      asm volatile("s_waitcnt lgkmcnt(0)" ::: "memory");
      __builtin_amdgcn_s_barrier();
      __builtin_amdgcn_sched_barrier(0);
    }
  }

  // epilogue: normalize, LDS transpose (otile overlays K0), write ot[bh][l][32]
  ushort* otile = &smem[0];   // [128][40]
  float rl0 = 1.f / oaccS[0][0];
  float rl1 = 1.f / oaccS[1][0];
#pragma unroll
  for (int md = 0; md < 2; ++md) {
    uint2 p0 = make_uint2(pkh(oacc[md][0][0] * rl0, oacc[md][0][1] * rl0),
                          pkh(oacc[md][0][2] * rl0, oacc[md][0][3] * rl0));
    uint2 p1 = make_uint2(pkh(oacc[md][1][0] * rl1, oacc[md][1][1] * rl1),
                          pkh(oacc[md][1][2] * rl1, oacc[md][1][3] * rl1));
    *(uint2*)&otile[(w * 32 + ln) * 40 + 16 * md + 4 * g] = p0;
    *(uint2*)&otile[(w * 32 + 16 + ln) * 40 + 16 * md + 4 * g] = p1;
  }
  __syncthreads();
  {
    int row = t >> 1, half = t & 1;
    uint4 v0 = *(const uint4*)&otile[row * 40 + half * 16];
    uint4 v1 = *(const uint4*)&otile[row * 40 + half * 16 + 8];
    ushort* dstp = ot + ((size_t)bh * L_ + q0b + row) * 32 + half * 16;
    *(uint4*)dstp = v0;
    *(uint4*)(dstp + 8) = v1;
  }
}

// ---------------------------------------------------------------------------
extern "C" void kernel_launch(void* const* d_in, const int* in_sizes, int n_in,
                              void* d_out, int out_size, void* d_ws, size_t ws_size,
                              hipStream_t stream) {
  const float* x      = (const float*)d_in[0];
  const float* gamma  = (const float*)d_in[1];
  const float* beta   = (const float*)d_in[2];
  const float* dw     = (const float*)d_in[3];
  const float* qkv_w  = (const float*)d_in[4];
  const float* qkv_b  = (const float*)d_in[5];
  const float* out_w  = (const float*)d_in[6];
  const float* out_b  = (const float*)d_in[7];
  float* out = (float*)d_out;

  char* ws = (char*)d_ws;
  ushort* ht   = (ushort*)(ws);                   // 4 MiB @0  (dead after qkv)
  ushort* qtb  = (ushort*)(ws + (16u << 20));     // 4 MiB @16
  ushort* ktb  = (ushort*)(ws + (20u << 20));     // 4 MiB @20
  ushort* vbb  = (ushort*)(ws + (24u << 20));     // 4 MiB @24
  ushort* otb  = (ushort*)(ws);                   // 4 MiB @0  (reuse ht)
  ushort* wq   = (ushort*)(ws + (28u << 20));     // 384 KiB @28M
  ushort* wo   = (ushort*)(ws + (28u << 20) + (512u << 10));  // 128 KiB

  gnw_kernel<<<512, 256, 0, stream>>>(x, gamma, beta, dw,
                                      (const float4*)qkv_w, (const float4*)out_w,
                                      (uint2*)wq, (uint2*)wo, ht);
  qkv_fused_kernel<<<dim3(8, 8, B_), 256, 0, stream>>>(ht, wq, qkv_b, qtb, ktb, vbb);
  attn_mfma_kernel<<<512, 256, 0, stream>>>(qtb, ktb, vbb, otb);
  outconv_kernel<<<dim3(8, 8, B_), 256, 0, stream>>>(otb, wo, out_b, x, out);
}

// Round 15
// 54.252 us; speedup vs baseline: 1.2961x; 1.0131x over previous
//
#include <hip/hip_runtime.h>
#include <hip/hip_bf16.h>

#define B_ 8
#define C_ 256
#define L_ 1024
#define NH_ 8
#define EPS_ 1e-5f

typedef __attribute__((ext_vector_type(8))) _Float16 half8;
typedef __attribute__((ext_vector_type(2))) __fp16 fp16x2;
typedef __attribute__((ext_vector_type(4))) float f32x4;

static __device__ inline ushort f2h(float f) {
  union { _Float16 h; ushort u; } c;
  c.h = (_Float16)f;
  return c.u;
}

// pack two fp32 -> fp16 pair via v_cvt_pkrtz_f16_f32 (compiler builtin --
// safe on TRANS-result inputs, unlike inline asm; rounds 9-11 lesson)
static __device__ inline uint pkh(float a, float b) {
  union { fp16x2 v; uint u; } c;
  c.v = __builtin_amdgcn_cvt_pkrtz(a, b);
  return c.u;
}

// ---------------------------------------------------------------------------
// Kernel A (512 threads): blocks 0-127: weight fp32->fp16 convert;
// blocks 128-383: GroupNorm + depthwise conv k=3 (8 waves/block for latency
// hiding; was 4 waves at 1 block/CU). Output ht [B][32 cg][1024 l][8 c].
// ---------------------------------------------------------------------------
__global__ __launch_bounds__(512) void gnw_kernel(
    const float* __restrict__ x, const float* __restrict__ gamma,
    const float* __restrict__ beta, const float* __restrict__ dw,
    const float4* __restrict__ qw, const float4* __restrict__ ow,
    uint2* __restrict__ wq, uint2* __restrict__ wo_,
    ushort* __restrict__ ht) {
  __shared__ float hn[8 * L_];
  __shared__ float ws0[8], ws1[8];
  int t = threadIdx.x;
  if (blockIdx.x < 128) {
    int id = blockIdx.x * 512 + t;
    float4 v;
    uint2* dst;
    if (id < 49152) { v = qw[id]; dst = wq + id; }
    else { v = ow[id - 49152]; dst = wo_ + (id - 49152); }
    *dst = make_uint2(pkh(v.x, v.y), pkh(v.z, v.w));
    return;
  }
  int blk = blockIdx.x - 128;     // b*32 + g
  int b = blk >> 5, g = blk & 31;
  const size_t base = ((size_t)(b * C_ + g * 8)) * L_;

  float s = 0.f, ss = 0.f;
  float vals[16];
#pragma unroll
  for (int i = 0; i < 16; ++i) {
    int e = t + 512 * i;
    float v = x[base + e];
    vals[i] = v;
    s += v; ss += v * v;
  }
#pragma unroll
  for (int off = 32; off >= 1; off >>= 1) {
    s  += __shfl_xor(s, off);
    ss += __shfl_xor(ss, off);
  }
  int wave = t >> 6;
  if ((t & 63) == 0) { ws0[wave] = s; ws1[wave] = ss; }
  __syncthreads();
  s = 0.f; ss = 0.f;
#pragma unroll
  for (int i = 0; i < 8; ++i) { s += ws0[i]; ss += ws1[i]; }
  float mean = s * (1.f / 8192.f);
  float var = ss * (1.f / 8192.f) - mean * mean;
  float rstd = rsqrtf(var + EPS_);

  // e = t + 512*i ; channel c_loc = i>>1 ; l = t + 512*(i&1)
#pragma unroll
  for (int i = 0; i < 16; ++i) {
    int e = t + 512 * i;
    int c = g * 8 + (i >> 1);
    float sc = gamma[c] * rstd;
    hn[e] = (vals[i] - mean) * sc + beta[c];
  }
  __syncthreads();
  float r[16];
#pragma unroll
  for (int i = 0; i < 16; ++i) {
    int e = t + 512 * i;
    int l = e & 1023;
    int c = g * 8 + (i >> 1);
    float w0 = dw[c * 3 + 0], w1 = dw[c * 3 + 1], w2 = dw[c * 3 + 2];
    float a = (l > 0) ? hn[e - 1] : 0.f;
    float m = hn[e];
    float z = (l < 1023) ? hn[e + 1] : 0.f;
    r[i] = w0 * a + w1 * m + w2 * z;
  }
#pragma unroll
  for (int li = 0; li < 2; ++li) {
    int l = t + 512 * li;
    uint4 pk;
    pk.x = pkh(r[0 + li],  r[2 + li]);
    pk.y = pkh(r[4 + li],  r[6 + li]);
    pk.z = pkh(r[8 + li],  r[10 + li]);
    pk.w = pkh(r[12 + li], r[14 + li]);
    *(uint4*)(ht + (((size_t)(b * 32 + g)) * L_ + l) * 8) = pk;
  }
}

// ---------------------------------------------------------------------------
// Kernel B: qkv pointwise conv via MFMA (fp16), fused repack epilogue.
// Input ht [B][32][1024][8]. Q PRE-SCALED by 1/sqrt(C)*log2(e).
// ---------------------------------------------------------------------------
__global__ __launch_bounds__(256) void qkv_fused_kernel(
    const ushort* __restrict__ Xt, const ushort* __restrict__ Wb,
    const float* __restrict__ bias, ushort* __restrict__ qt,
    ushort* __restrict__ kt, ushort* __restrict__ vb) {
  int bx = blockIdx.x, head = blockIdx.y, b = blockIdx.z;
  int bh = b * 8 + head;
  int t = threadIdx.x;
  int w = t >> 6, l = t & 63;
  int g = l >> 4, ln = l & 15;
  int wl = w >> 1, wo = w & 1;
  int lbase = bx * 128 + wl * 64;

  const ushort* xb = Xt + (size_t)b * (32 * L_ * 8);
  const ushort* wp = Wb + (size_t)(head * 96 + wo * 48) * 256;

  f32x4 acc[4][3];
#pragma unroll
  for (int ml = 0; ml < 4; ++ml)
#pragma unroll
    for (int nn = 0; nn < 3; ++nn) acc[ml][nn] = (f32x4){0.f, 0.f, 0.f, 0.f};

  for (int c0 = 0; c0 < 256; c0 += 32) {
    half8 af[4], bf[3];
#pragma unroll
    for (int ml = 0; ml < 4; ++ml)
      af[ml] = *(const half8*)(xb +
          (((size_t)((c0 >> 3) + g)) * L_ + lbase + 16 * ml + ln) * 8);
#pragma unroll
    for (int nn = 0; nn < 3; ++nn)
      bf[nn] = *(const half8*)(wp + (size_t)(16 * nn + ln) * 256 + c0 + 8 * g);
#pragma unroll
    for (int ml = 0; ml < 4; ++ml)
#pragma unroll
      for (int nn = 0; nn < 3; ++nn)
        acc[ml][nn] = __builtin_amdgcn_mfma_f32_16x16x32_f16(af[ml], bf[nn], acc[ml][nn], 0, 0, 0);
  }

  // bias
#pragma unroll
  for (int nn = 0; nn < 3; ++nn) {
    float bs = bias[head * 96 + wo * 48 + 16 * nn + ln];
#pragma unroll
    for (int ml = 0; ml < 4; ++ml)
#pragma unroll
      for (int r = 0; r < 4; ++r) acc[ml][nn][r] += bs;
  }

  __shared__ ushort tr[5120];
  const float QSC = 0.0625f * 1.44269504f;   // 1/sqrt(256) * log2(e)

  // rounds 0 (q, scaled), 1 (k): transpose to [l][d] (pad 40), write [bh][l][32]
  for (int rk = 0; rk < 2; ++rk) {
    float sc = rk ? 1.f : QSC;
    __syncthreads();
#pragma unroll
    for (int nn = 0; nn < 3; ++nn) {
      int ocl0 = wo * 48 + 16 * nn;
      if (ocl0 >= rk * 32 && ocl0 < rk * 32 + 32) {
        int d = ocl0 - rk * 32 + ln;
#pragma unroll
        for (int ml = 0; ml < 4; ++ml) {
          int lrow = wl * 64 + 16 * ml + 4 * g;
#pragma unroll
          for (int r = 0; r < 4; ++r)
            tr[(lrow + r) * 40 + d] = f2h(acc[ml][nn][r] * sc);
        }
      }
    }
    __syncthreads();
    {
      int row = t >> 1, half = t & 1;
      uint4 v0 = *(const uint4*)&tr[row * 40 + half * 16];
      uint4 v1 = *(const uint4*)&tr[row * 40 + half * 16 + 8];
      ushort* dst = (rk ? kt : qt) +
                    ((size_t)bh * L_ + bx * 128 + row) * 32 + half * 16;
      *(uint4*)dst = v0;
      *(uint4*)(dst + 8) = v1;
    }
  }

  // round 2 (v): [d][l] (pad 136), PI-permute on global write
  __syncthreads();
  if (wo == 1) {
#pragma unroll
    for (int nn = 1; nn < 3; ++nn) {
      int d = 16 * (nn - 1) + ln;
#pragma unroll
      for (int ml = 0; ml < 4; ++ml) {
        int lc = wl * 64 + 16 * ml + 4 * g;
        *(uint2*)&tr[d * 136 + lc] =
            make_uint2(pkh(acc[ml][nn][0], acc[ml][nn][1]),
                       pkh(acc[ml][nn][2], acc[ml][nn][3]));
      }
    }
  }
  __syncthreads();
  {
    int d = t >> 3, s0 = t & 7;
    ushort* vdst = vb + ((size_t)bh * 32 + d) * L_ + bx * 128;
#pragma unroll
    for (int c = 0; c < 2; ++c) {
      int ch = s0 + 8 * c;
      int jj = ch >> 2, gg = ch & 3;
      uint2 lo = *(const uint2*)&tr[d * 136 + 32 * jj + 4 * gg];
      uint2 hi = *(const uint2*)&tr[d * 136 + 32 * jj + 16 + 4 * gg];
      *(uint4*)(vdst + 32 * jj + 8 * gg) = make_uint4(lo.x, lo.y, hi.x, hi.y);
    }
  }
}

// ---------------------------------------------------------------------------
// Kernel D: out pointwise conv via MFMA (fp16) + residual. Input ot
// [bh][1024][32]. Block = 128 l x 64 oc (wave = 128l x 16oc, acc[8]) -> ot
// re-read 4x instead of 8x. grid (8 ltile, 4 ocblk, B) = 256.
// ---------------------------------------------------------------------------
__global__ __launch_bounds__(256) void outconv_kernel(
    const ushort* __restrict__ Xt, const ushort* __restrict__ Wb,
    const float* __restrict__ bias, const float* __restrict__ resid,
    float* __restrict__ out) {
  int b = blockIdx.z;
  int t = threadIdx.x;
  int w = t >> 6, l = t & 63;
  int g = l >> 4, ln = l & 15;
  int lbase = blockIdx.x * 128;
  int ocblk = blockIdx.y * 64;
  int ocbase = ocblk + w * 16;

  const ushort* xb = Xt + (size_t)b * (8 * L_ * 32);
  const ushort* wp = Wb + (size_t)ocbase * 256;

  f32x4 acc[8];
#pragma unroll
  for (int ml = 0; ml < 8; ++ml) acc[ml] = (f32x4){0.f, 0.f, 0.f, 0.f};

  for (int c0 = 0; c0 < 256; c0 += 32) {
    half8 af[8];
#pragma unroll
    for (int ml = 0; ml < 8; ++ml)
      af[ml] = *(const half8*)(xb +
          ((size_t)(c0 >> 5) * L_ + lbase + 16 * ml + ln) * 32 + 8 * g);
    half8 bf = *(const half8*)(wp + (size_t)ln * 256 + c0 + 8 * g);
#pragma unroll
    for (int ml = 0; ml < 8; ++ml)
      acc[ml] = __builtin_amdgcn_mfma_f32_16x16x32_f16(af[ml], bf, acc[ml], 0, 0, 0);
  }

  __shared__ float tile[64][132];   // 33 KB
  float bs = bias[ocbase + ln];
#pragma unroll
  for (int ml = 0; ml < 8; ++ml) {
    int ll = 16 * ml + 4 * g;
    float4 v = make_float4(acc[ml][0] + bs, acc[ml][1] + bs,
                           acc[ml][2] + bs, acc[ml][3] + bs);
    *(float4*)&tile[w * 16 + ln][ll] = v;
  }
  __syncthreads();
  {
    int ocl = t >> 2, lq = t & 3;           // 64 oc x 4 l-chunks of 32
    const float* src = &tile[ocl][lq * 32];
    size_t ob = ((size_t)b * 256 + ocblk + ocl) * L_ + lbase + lq * 32;
#pragma unroll
    for (int i = 0; i < 8; ++i) {
      float4 v = *(const float4*)(src + 4 * i);
      float4 rd = *(const float4*)(resid + ob + 4 * i);
      v.x += rd.x; v.y += rd.y; v.z += rd.z; v.w += rd.w;
      *(float4*)(out + ob + 4 * i) = v;
    }
  }
}

// ---------------------------------------------------------------------------
// Kernel C: MFMA flash attention (fp16 pipeline), no max-subtraction.
// exp via v_exp_f32 builtin; P-pack via cvt_pkrtz builtin (1 op / 2 elems).
// dbuf LDS staging, padded layouts, otile overlays K0. grid 512, 4 blk/CU.
// ---------------------------------------------------------------------------
__global__ __launch_bounds__(256) void attn_mfma_kernel(
    const ushort* __restrict__ qt, const ushort* __restrict__ kt,
    const ushort* __restrict__ vb, ushort* __restrict__ ot) {
  const int id = blockIdx.x;
  const int bh = ((id & 7) << 3) | (id >> 6);
  const int qtile = (id >> 3) & 7;
  const int t = threadIdx.x;
  const int w = t >> 6, l = t & 63;
  const int g = l >> 4, ln = l & 15;
  const int q0b = qtile * 128;
  const int q0 = q0b + w * 32;

  // smem (ushorts): K0 @0 (5120), K1 @5120, V0 @10240 (4352), V1 @14592.
  // otile [128][40] = 5120 overlays K0 (dead in tt=7 / epilogue).
  __shared__ __align__(16) ushort smem[18944];   // 37,888 B

  const ushort* qbase = qt + (size_t)bh * (L_ * 32);
  const ushort* kbase = kt + (size_t)bh * (L_ * 32);
  const ushort* vbase = vb + (size_t)bh * (32 * L_);

  // staging geometry
  const int krow = t >> 1, khalf = t & 1;
  const ushort* kg = kbase + krow * 32 + khalf * 16;
  const int kwo = krow * 40 + khalf * 16;
  const int vrow = t >> 3, vc = (t & 7) * 16;
  const ushort* vg = vbase + (size_t)vrow * L_ + vc;
  const int vwo = vrow * 136 + vc;

  const f32x4 z4 = {0.f, 0.f, 0.f, 0.f};
  half8 bq[2];
  bq[0] = *(const half8*)(qbase + (size_t)(q0 + ln) * 32 + g * 8);
  bq[1] = *(const half8*)(qbase + (size_t)(q0 + 16 + ln) * 32 + g * 8);

  union { ushort s[8]; half8 v; } onesu;
#pragma unroll
  for (int i = 0; i < 8; ++i) onesu.s[i] = 0x3C00;  // fp16 1.0
  const half8 ones = onesu.v;

  f32x4 oacc[2][2];  // [md][nq]
  oacc[0][0] = z4; oacc[0][1] = z4; oacc[1][0] = z4; oacc[1][1] = z4;
  f32x4 oaccS[2] = {z4, z4};

  // prologue: stage tile 0
  uint4 ka0, ka1, va0, va1;
  ka0 = *(const uint4*)kg;       ka1 = *(const uint4*)(kg + 8);
  va0 = *(const uint4*)vg;       va1 = *(const uint4*)(vg + 8);
  __builtin_amdgcn_sched_barrier(0);
  *(uint4*)&smem[kwo] = ka0;             *(uint4*)&smem[kwo + 8] = ka1;
  *(uint4*)&smem[10240 + vwo] = va0;     *(uint4*)&smem[10240 + vwo + 8] = va1;
  asm volatile("s_waitcnt lgkmcnt(0)" ::: "memory");
  __builtin_amdgcn_s_barrier();
  __builtin_amdgcn_sched_barrier(0);

  for (int tt = 0; tt < 8; ++tt) {
    const int cur = tt & 1;
    if (tt < 7) {
      ka0 = *(const uint4*)(kg + (tt + 1) * 4096);
      ka1 = *(const uint4*)(kg + (tt + 1) * 4096 + 8);
      va0 = *(const uint4*)(vg + (tt + 1) * 128);
      va1 = *(const uint4*)(vg + (tt + 1) * 128 + 8);
    }
    __builtin_amdgcn_sched_barrier(0);

    const ushort* Kc = &smem[cur * 5120];
    const ushort* Vc = &smem[10240 + cur * 4352];

    // QK^T  (S already in log2-units thanks to Q pre-scale)
    f32x4 sacc[8][2];
#pragma unroll
    for (int mk = 0; mk < 8; ++mk) {
      half8 ak = *(const half8*)(Kc + (16 * mk + ln) * 40 + g * 8);
      sacc[mk][0] = __builtin_amdgcn_mfma_f32_16x16x32_f16(ak, bq[0], z4, 0, 0, 0);
      sacc[mk][1] = __builtin_amdgcn_mfma_f32_16x16x32_f16(ak, bq[1], z4, 0, 0, 0);
    }

    // exp via v_exp_f32; pack pairs via cvt_pkrtz (compiler builtin -- safe
    // TRANS consumer, 1 op per 2 elems)
    uint upk[2][8][2];
#pragma unroll
    for (int nq = 0; nq < 2; ++nq) {
#pragma unroll
      for (int mk = 0; mk < 8; ++mk) {
        float e0 = __builtin_amdgcn_exp2f(sacc[mk][nq][0]);
        float e1 = __builtin_amdgcn_exp2f(sacc[mk][nq][1]);
        float e2 = __builtin_amdgcn_exp2f(sacc[mk][nq][2]);
        float e3 = __builtin_amdgcn_exp2f(sacc[mk][nq][3]);
        upk[nq][mk][0] = pkh(e0, e1);
        upk[nq][mk][1] = pkh(e2, e3);
      }
    }

    // PV + denominator
#pragma unroll
    for (int ks = 0; ks < 4; ++ks) {
      union { uint u[4]; half8 v; } pb0, pb1;
      pb0.u[0] = upk[0][2 * ks][0]; pb0.u[1] = upk[0][2 * ks][1];
      pb0.u[2] = upk[0][2 * ks + 1][0]; pb0.u[3] = upk[0][2 * ks + 1][1];
      pb1.u[0] = upk[1][2 * ks][0]; pb1.u[1] = upk[1][2 * ks][1];
      pb1.u[2] = upk[1][2 * ks + 1][0]; pb1.u[3] = upk[1][2 * ks + 1][1];
      oaccS[0] = __builtin_amdgcn_mfma_f32_16x16x32_f16(ones, pb0.v, oaccS[0], 0, 0, 0);
      oaccS[1] = __builtin_amdgcn_mfma_f32_16x16x32_f16(ones, pb1.v, oaccS[1], 0, 0, 0);
#pragma unroll
      for (int md = 0; md < 2; ++md) {
        half8 av = *(const half8*)(Vc + (16 * md + ln) * 136 + 32 * ks + 8 * g);
        oacc[md][0] = __builtin_amdgcn_mfma_f32_16x16x32_f16(av, pb0.v, oacc[md][0], 0, 0, 0);
        oacc[md][1] = __builtin_amdgcn_mfma_f32_16x16x32_f16(av, pb1.v, oacc[md][1], 0, 0, 0);
      }
    }

    __builtin_amdgcn_sched_barrier(0);
    if (tt < 7) {
      const int nxt = cur ^ 1;
      *(uint4*)&smem[nxt * 5120 + kwo] = ka0;
      *(uint4*)&smem[nxt * 5120 + kwo + 8] = ka1;
      *(uint4*)&smem[10240 + nxt * 4352 + vwo] = va0;
      *(uint4*)&smem[10240 + nxt * 4352 + vwo + 8] = va1;
      asm volatile("s_waitcnt lgkmcnt(0)" ::: "memory");
      __builtin_amdgcn_s_barrier();
      __builtin_amdgcn_sched_barrier(0);
    }
  }

  // epilogue: normalize, LDS transpose (otile overlays K0), write ot[bh][l][32]
  ushort* otile = &smem[0];   // [128][40]
  float rl0 = 1.f / oaccS[0][0];
  float rl1 = 1.f / oaccS[1][0];
#pragma unroll
  for (int md = 0; md < 2; ++md) {
    uint2 p0 = make_uint2(pkh(oacc[md][0][0] * rl0, oacc[md][0][1] * rl0),
                          pkh(oacc[md][0][2] * rl0, oacc[md][0][3] * rl0));
    uint2 p1 = make_uint2(pkh(oacc[md][1][0] * rl1, oacc[md][1][1] * rl1),
                          pkh(oacc[md][1][2] * rl1, oacc[md][1][3] * rl1));
    *(uint2*)&otile[(w * 32 + ln) * 40 + 16 * md + 4 * g] = p0;
    *(uint2*)&otile[(w * 32 + 16 + ln) * 40 + 16 * md + 4 * g] = p1;
  }
  __syncthreads();
  {
    int row = t >> 1, half = t & 1;
    uint4 v0 = *(const uint4*)&otile[row * 40 + half * 16];
    uint4 v1 = *(const uint4*)&otile[row * 40 + half * 16 + 8];
    ushort* dstp = ot + ((size_t)bh * L_ + q0b + row) * 32 + half * 16;
    *(uint4*)dstp = v0;
    *(uint4*)(dstp + 8) = v1;
  }
}

// ---------------------------------------------------------------------------
extern "C" void kernel_launch(void* const* d_in, const int* in_sizes, int n_in,
                              void* d_out, int out_size, void* d_ws, size_t ws_size,
                              hipStream_t stream) {
  const float* x      = (const float*)d_in[0];
  const float* gamma  = (const float*)d_in[1];
  const float* beta   = (const float*)d_in[2];
  const float* dw     = (const float*)d_in[3];
  const float* qkv_w  = (const float*)d_in[4];
  const float* qkv_b  = (const float*)d_in[5];
  const float* out_w  = (const float*)d_in[6];
  const float* out_b  = (const float*)d_in[7];
  float* out = (float*)d_out;

  char* ws = (char*)d_ws;
  ushort* ht   = (ushort*)(ws);                   // 4 MiB @0  (dead after qkv)
  ushort* qtb  = (ushort*)(ws + (16u << 20));     // 4 MiB @16
  ushort* ktb  = (ushort*)(ws + (20u << 20));     // 4 MiB @20
  ushort* vbb  = (ushort*)(ws + (24u << 20));     // 4 MiB @24
  ushort* otb  = (ushort*)(ws);                   // 4 MiB @0  (reuse ht)
  ushort* wq   = (ushort*)(ws + (28u << 20));     // 384 KiB @28M
  ushort* wo   = (ushort*)(ws + (28u << 20) + (512u << 10));  // 128 KiB

  gnw_kernel<<<384, 512, 0, stream>>>(x, gamma, beta, dw,
                                      (const float4*)qkv_w, (const float4*)out_w,
                                      (uint2*)wq, (uint2*)wo, ht);
  qkv_fused_kernel<<<dim3(8, 8, B_), 256, 0, stream>>>(ht, wq, qkv_b, qtb, ktb, vbb);
  attn_mfma_kernel<<<512, 256, 0, stream>>>(qtb, ktb, vbb, otb);
  outconv_kernel<<<dim3(8, 4, B_), 256, 0, stream>>>(otb, wo, out_b, x, out);
}